// Round 1
// baseline (499.534 us; speedup 1.0000x reference)
//
#include <hip/hip_runtime.h>

static constexpr float SCALE = 0.08838834764831845f; // 1/sqrt(128)

// =====================================================================
// proj GEMM: C = A @ W^T + bias.  A:(1024x1024) row-major, W:(1024x1024)
// row-major (N,K).  LAYOUT 0: plain C[m*1024+n] (B,S,D)
// LAYOUT 1: C[((b*8+h)*512+i)*128+dk]  (B,H,S,DK)
// =====================================================================
template<int LAYOUT>
__global__ __launch_bounds__(256)
void proj_gemm(const float* __restrict__ A, const float* __restrict__ W,
               const float* __restrict__ bias, float* __restrict__ C)
{
  const int m0 = (blockIdx.x >> 4) << 6;
  const int n0 = (blockIdx.x & 15) << 6;
  __shared__ float As[16][64];
  __shared__ float Ws[16][64];
  const int t  = threadIdx.x;
  const int tm = t >> 4, tn = t & 15;
  const int lr = t >> 2;
  const int lc = (t & 3) << 2;
  float acc[4][4] = {};
  for (int k0 = 0; k0 < 1024; k0 += 16) {
    const float4 av = *(const float4*)&A[(size_t)(m0 + lr) * 1024 + k0 + lc];
    const float4 wv = *(const float4*)&W[(size_t)(n0 + lr) * 1024 + k0 + lc];
    __syncthreads();
    As[lc+0][lr] = av.x; As[lc+1][lr] = av.y; As[lc+2][lr] = av.z; As[lc+3][lr] = av.w;
    Ws[lc+0][lr] = wv.x; Ws[lc+1][lr] = wv.y; Ws[lc+2][lr] = wv.z; Ws[lc+3][lr] = wv.w;
    __syncthreads();
#pragma unroll
    for (int kk = 0; kk < 16; ++kk) {
      float a[4], w[4];
      *(float4*)a = *(const float4*)&As[kk][tm << 2];
      *(float4*)w = *(const float4*)&Ws[kk][tn << 2];
#pragma unroll
      for (int r = 0; r < 4; ++r)
#pragma unroll
        for (int c = 0; c < 4; ++c)
          acc[r][c] = fmaf(a[r], w[c], acc[r][c]);
    }
  }
  const int rb = m0 + (tm << 2), cb = n0 + (tn << 2);
#pragma unroll
  for (int r = 0; r < 4; ++r) {
#pragma unroll
    for (int c = 0; c < 4; ++c) {
      const int m = rb + r, n = cb + c;
      const float val = acc[r][c] + bias[n];
      if (LAYOUT == 0) {
        C[(size_t)m * 1024 + n] = val;
      } else {
        const int b = m >> 9, i = m & 511, h = n >> 7, dk = n & 127;
        C[(((size_t)(b * 8 + h) * 512) + i) * 128 + dk] = val;
      }
    }
  }
}

// =====================================================================
// QK^T batched GEMM: scores[bh] += q[bh] @ k[bh]^T  (M=N=512, K=128)
// (relk_kernel has already written the relation part into scores)
// =====================================================================
__global__ __launch_bounds__(256)
void qk_gemm(const float* __restrict__ qb, const float* __restrict__ kb,
             float* __restrict__ scores)
{
  const int bh = blockIdx.y;
  const float* A  = qb + (size_t)bh * (512 * 128);
  const float* Bw = kb + (size_t)bh * (512 * 128);
  float* C = scores + (size_t)bh * (512 * 512);
  const int m0 = (blockIdx.x >> 3) << 6;
  const int n0 = (blockIdx.x & 7) << 6;
  __shared__ float As[16][64];
  __shared__ float Ws[16][64];
  const int t  = threadIdx.x;
  const int tm = t >> 4, tn = t & 15;
  const int lr = t >> 2;
  const int lc = (t & 3) << 2;
  float acc[4][4] = {};
  for (int k0 = 0; k0 < 128; k0 += 16) {
    const float4 av = *(const float4*)&A [(size_t)(m0 + lr) * 128 + k0 + lc];
    const float4 wv = *(const float4*)&Bw[(size_t)(n0 + lr) * 128 + k0 + lc];
    __syncthreads();
    As[lc+0][lr] = av.x; As[lc+1][lr] = av.y; As[lc+2][lr] = av.z; As[lc+3][lr] = av.w;
    Ws[lc+0][lr] = wv.x; Ws[lc+1][lr] = wv.y; Ws[lc+2][lr] = wv.z; Ws[lc+3][lr] = wv.w;
    __syncthreads();
#pragma unroll
    for (int kk = 0; kk < 16; ++kk) {
      float a[4], w[4];
      *(float4*)a = *(const float4*)&As[kk][tm << 2];
      *(float4*)w = *(const float4*)&Ws[kk][tn << 2];
#pragma unroll
      for (int r = 0; r < 4; ++r)
#pragma unroll
        for (int c = 0; c < 4; ++c)
          acc[r][c] = fmaf(a[r], w[c], acc[r][c]);
    }
  }
  const int rb = m0 + (tm << 2), cb = n0 + (tn << 2);
#pragma unroll
  for (int r = 0; r < 4; ++r)
#pragma unroll
    for (int c = 0; c < 4; ++c) {
      const size_t idx = (size_t)(rb + r) * 512 + cb + c;
      C[idx] += acc[r][c];
    }
}

// =====================================================================
// PV batched GEMM: x[b, i, h*128+d] += p[bh] @ v[bh]   (M=512,N=128,K=512)
// (relv_kernel already wrote the relation part into x)
// =====================================================================
__global__ __launch_bounds__(256)
void pv_gemm(const float* __restrict__ p, const float* __restrict__ vb,
             float* __restrict__ x)
{
  const int bh = blockIdx.y, b = bh >> 3, h = bh & 7;
  const float* A  = p  + (size_t)bh * (512 * 512);
  const float* Bw = vb + (size_t)bh * (512 * 128);
  float* C = x + (size_t)b * (512 * 1024) + h * 128;
  const int m0 = (blockIdx.x >> 1) << 6;
  const int n0 = (blockIdx.x & 1) << 6;
  __shared__ float As[16][64];
  __shared__ float Bs[16][64];
  const int t  = threadIdx.x;
  const int tm = t >> 4, tn = t & 15;
  const int lr = t >> 2;
  const int lc = (t & 3) << 2;
  const int bk = t >> 4, bn = (t & 15) << 2;
  float acc[4][4] = {};
  for (int k0 = 0; k0 < 512; k0 += 16) {
    const float4 av = *(const float4*)&A [(size_t)(m0 + lr) * 512 + k0 + lc];
    const float4 bv = *(const float4*)&Bw[(size_t)(k0 + bk) * 128 + n0 + bn];
    __syncthreads();
    As[lc+0][lr] = av.x; As[lc+1][lr] = av.y; As[lc+2][lr] = av.z; As[lc+3][lr] = av.w;
    *(float4*)&Bs[bk][bn] = bv;
    __syncthreads();
#pragma unroll
    for (int kk = 0; kk < 16; ++kk) {
      float a[4], w[4];
      *(float4*)a = *(const float4*)&As[kk][tm << 2];
      *(float4*)w = *(const float4*)&Bs[kk][tn << 2];
#pragma unroll
      for (int r = 0; r < 4; ++r)
#pragma unroll
        for (int c = 0; c < 4; ++c)
          acc[r][c] = fmaf(a[r], w[c], acc[r][c]);
    }
  }
  const int rb = m0 + (tm << 2), cb = n0 + (tn << 2);
#pragma unroll
  for (int r = 0; r < 4; ++r)
#pragma unroll
    for (int c = 0; c < 4; ++c) {
      const size_t idx = (size_t)(rb + r) * 1024 + cb + c;
      C[idx] += acc[r][c];
    }
}

// =====================================================================
// relation_k kernel: per (b,i) block, streams rk[b,i,:,:] (256 KB) and
// writes scores[b,h,i,j] = q[b,h,i,:] . rk[b,i,j,:]   (raw, unscaled)
// =====================================================================
__global__ __launch_bounds__(256)
void relk_kernel(const float* __restrict__ qb, const float* __restrict__ rk,
                 float* __restrict__ scores)
{
  const int bi = blockIdx.x;
  const int b = bi >> 9, i = bi & 511;
  __shared__ float qs[8][144];     // sub-slice stride 36 -> conflict-free f4 reads
  const int t = threadIdx.x;
  {
    const int h = t >> 5, d0 = (t & 31) << 2;
    const int sub = d0 >> 5, dd = d0 & 31;
    const float4 qv = *(const float4*)&qb[(((size_t)(b * 8 + h) * 512) + i) * 128 + d0];
    *(float4*)&qs[h][sub * 36 + dd] = qv;
  }
  __syncthreads();
  const int jj = t >> 2, sub = t & 3;
  for (int jp = 0; jp < 512; jp += 64) {
    const int j = jp + jj;
    const float* rkp = rk + ((size_t)bi * 512 + j) * 128 + sub * 32;
    float rvl[32];
#pragma unroll
    for (int u = 0; u < 8; ++u)
      *(float4*)&rvl[u * 4] = *(const float4*)&rkp[u * 4];
    float acc[8];
#pragma unroll
    for (int h = 0; h < 8; ++h) acc[h] = 0.f;
#pragma unroll
    for (int d4 = 0; d4 < 8; ++d4) {
#pragma unroll
      for (int h = 0; h < 8; ++h) {
        const float4 qv = *(const float4*)&qs[h][sub * 36 + (d4 << 2)];
        acc[h] = fmaf(qv.x, rvl[d4*4+0], acc[h]);
        acc[h] = fmaf(qv.y, rvl[d4*4+1], acc[h]);
        acc[h] = fmaf(qv.z, rvl[d4*4+2], acc[h]);
        acc[h] = fmaf(qv.w, rvl[d4*4+3], acc[h]);
      }
    }
#pragma unroll
    for (int h = 0; h < 8; ++h) {
      acc[h] += __shfl_xor(acc[h], 1);
      acc[h] += __shfl_xor(acc[h], 2);
    }
    const int h0 = sub << 1;
    scores[(((size_t)(b*8 + h0  ) * 512) + i) * 512 + j] = acc[h0];
    scores[(((size_t)(b*8 + h0+1) * 512) + i) * 512 + j] = acc[h0+1];
  }
}

// =====================================================================
// relation_v kernel: per (b,i) block, streams rv[b,i,:,:] and writes
// x[b,i,h*128+d] = sum_j p[b,h,i,j]*rv[b,i,j,d]
// =====================================================================
__global__ __launch_bounds__(256)
void relv_kernel(const float* __restrict__ p, const float* __restrict__ rvg,
                 float* __restrict__ x)
{
  const int bi = blockIdx.x, b = bi >> 9, i = bi & 511;
  __shared__ float ps[8][512];
  const int t = threadIdx.x;
  for (int i4 = t; i4 < 1024; i4 += 256) {
    const int h = i4 >> 7, j0 = (i4 & 127) << 2;
    *(float4*)&ps[h][j0] =
        *(const float4*)&p[(((size_t)(b*8 + h) * 512) + i) * 512 + j0];
  }
  __syncthreads();
  const int h = t >> 5, d0 = (t & 31) << 2;
  const float* rp = rvg + (size_t)bi * 512 * 128 + d0;
  float4 acc = make_float4(0.f, 0.f, 0.f, 0.f);
  for (int j = 0; j < 512; j += 8) {
    float4 rr[8];
#pragma unroll
    for (int u = 0; u < 8; ++u)
      rr[u] = *(const float4*)&rp[(size_t)(j + u) * 128];
#pragma unroll
    for (int u = 0; u < 8; ++u) {
      const float w = ps[h][j + u];
      acc.x = fmaf(w, rr[u].x, acc.x);
      acc.y = fmaf(w, rr[u].y, acc.y);
      acc.z = fmaf(w, rr[u].z, acc.z);
      acc.w = fmaf(w, rr[u].w, acc.w);
    }
  }
  *(float4*)&x[((size_t)(b * 512 + i)) * 1024 + h * 128 + d0] = acc;
}

// =====================================================================
// sep / gating / loss kernel (single block).  Needs q only.
// Writes g[b,h,p] and loss -> out[B*S*D].
// =====================================================================
__global__ __launch_bounds__(256)
void sep_kernel(const float* __restrict__ qb, const float* __restrict__ hw,
                const int* __restrict__ sep_id, const float* __restrict__ hreg,
                float* __restrict__ g, float* __restrict__ loss_out)
{
  __shared__ float pool[16][4];
  __shared__ float spred[16][4];
  __shared__ float lbuf[16];
  __shared__ int sids[4];
  const int t = threadIdx.x;
  if (t < 4) sids[t] = sep_id[t];
  __syncthreads();
  // 64 dots (bh,n) x 4 threads each over 32 d's
  {
    const int dot = t >> 2, sub = t & 3;
    const int bh = dot >> 2, n = dot & 3;
    const int b = bh >> 3, h = bh & 7;
    const int row = sids[n];
    const float* qp = qb + (((size_t)(b * 8 + h) * 512) + row) * 128 + sub * 32;
    const float* wp = hw + h * 128 + sub * 32;
    float s = 0.f;
#pragma unroll
    for (int dd = 0; dd < 32; ++dd) s = fmaf(qp[dd], wp[dd], s);
    s += __shfl_xor(s, 1);
    s += __shfl_xor(s, 2);
    if (sub == 0) { pool[bh][n] = s; }
  }
  __syncthreads();
  if (t < 16) {
    float pv[4];
#pragma unroll
    for (int n = 0; n < 4; ++n) pv[n] = pool[t][n];
    float mx = fmaxf(fmaxf(pv[0], pv[1]), fmaxf(pv[2], pv[3]));
    float sum = 0.f;
#pragma unroll
    for (int n = 0; n < 4; ++n) { pv[n] = expf(pv[n] - mx); sum += pv[n]; }
    const float inv = 1.f / sum;
    float maxp = 0.f, l2 = 0.f;
#pragma unroll
    for (int n = 0; n < 4; ++n) {
      const float pr = pv[n] * inv;
      spred[t][n] = pr;
      maxp = fmaxf(maxp, pr);
      const float tg = hreg[n];
      l2 += tg * (logf(tg) - logf(pr));
    }
    lbuf[t] = (1.f - maxp) / 16.f + l2 / 64.f;
  }
  __syncthreads();
  if (t == 0) {
    float L = 0.f;
#pragma unroll
    for (int r = 0; r < 16; ++r) L += lbuf[r];
    loss_out[0] = L;
  }
  // g[b,h,p] = sum_n spred * (p >= sep_id[n])
  for (int idx = t; idx < 16 * 512; idx += 256) {
    const int bh = idx >> 9, pp = idx & 511;
    float gg = 0.f;
#pragma unroll
    for (int n = 0; n < 4; ++n)
      gg += spred[bh][n] * (pp >= sids[n] ? 1.f : 0.f);
    g[idx] = gg;
  }
}

// =====================================================================
// softmax kernel: one wave per (b,h,i) row.
// scores = softmax( (raw*scale masked) * factor )
// factor[j] = g[b,h,min(i,j)]
// =====================================================================
__global__ __launch_bounds__(64)
void softmax_kernel(float* __restrict__ scores, const int* __restrict__ mask,
                    const float* __restrict__ g)
{
  const int bhi = blockIdx.x;
  const int i = bhi & 511;
  const int bh = bhi >> 9;
  const int b = bh >> 3;
  float* row = scores + (size_t)bhi * 512;
  const int* mrow = mask + ((size_t)(b * 512 + i)) * 512;
  const float* grow = g + bh * 512;
  const float gi = grow[i];
  const int j0 = threadIdx.x << 3;
  float va[8];
  *(float4*)&va[0] = *(const float4*)&row[j0];
  *(float4*)&va[4] = *(const float4*)&row[j0 + 4];
  int ma[8];
  *(int4*)&ma[0] = *(const int4*)&mrow[j0];
  *(int4*)&ma[4] = *(const int4*)&mrow[j0 + 4];
  float ga[8];
  *(float4*)&ga[0] = *(const float4*)&grow[j0];
  *(float4*)&ga[4] = *(const float4*)&grow[j0 + 4];
  float mx = -3.402823466e+38f;
#pragma unroll
  for (int u = 0; u < 8; ++u) {
    const int j = j0 + u;
    float s = va[u] * SCALE;
    if (ma[u] == 0) s = -1.0e9f;
    const float fac = (j >= i) ? gi : ga[u];
    s *= fac;
    va[u] = s;
    mx = fmaxf(mx, s);
  }
#pragma unroll
  for (int off = 32; off > 0; off >>= 1) mx = fmaxf(mx, __shfl_xor(mx, off));
  float sum = 0.f;
#pragma unroll
  for (int u = 0; u < 8; ++u) { const float e = __expf(va[u] - mx); va[u] = e; sum += e; }
#pragma unroll
  for (int off = 32; off > 0; off >>= 1) sum += __shfl_xor(sum, off);
  const float inv = 1.f / sum;
#pragma unroll
  for (int u = 0; u < 8; ++u) va[u] *= inv;
  *(float4*)&row[j0]     = *(const float4*)&va[0];
  *(float4*)&row[j0 + 4] = *(const float4*)&va[4];
}

// =====================================================================
extern "C" void kernel_launch(void* const* d_in, const int* in_sizes, int n_in,
                              void* d_out, int out_size, void* d_ws, size_t ws_size,
                              hipStream_t stream)
{
  const float* query = (const float*)d_in[0];
  const float* key   = (const float*)d_in[1];
  const float* value = (const float*)d_in[2];
  const float* rk    = (const float*)d_in[3];
  const float* rv    = (const float*)d_in[4];
  const int*   mask  = (const int*)d_in[5];
  const int*   sep   = (const int*)d_in[6];
  const float* hreg  = (const float*)d_in[7];
  const float* Wq    = (const float*)d_in[8];
  const float* bq    = (const float*)d_in[9];
  const float* Wk    = (const float*)d_in[10];
  const float* bk    = (const float*)d_in[11];
  const float* Wv    = (const float*)d_in[12];
  const float* bv    = (const float*)d_in[13];
  const float* Wo    = (const float*)d_in[14];
  const float* bo    = (const float*)d_in[15];
  const float* hw    = (const float*)d_in[16];
  float* out = (float*)d_out;

  float* ws = (float*)d_ws;
  float* qb = ws;                         // 1,048,576
  float* kb = qb + 1048576;               // 1,048,576
  float* vb = kb + 1048576;               // 1,048,576
  float* sc = vb + 1048576;               // 4,194,304
  float* xb = sc + 4194304;               // 1,048,576
  float* gb = xb + 1048576;               // 8,192
  // total ~33.6 MB of workspace

  proj_gemm<1><<<dim3(256), 256, 0, stream>>>(query, Wq, bq, qb);
  proj_gemm<1><<<dim3(256), 256, 0, stream>>>(key,   Wk, bk, kb);
  proj_gemm<1><<<dim3(256), 256, 0, stream>>>(value, Wv, bv, vb);
  sep_kernel<<<dim3(1), 256, 0, stream>>>(qb, hw, sep, hreg, gb, out + 1048576);
  relk_kernel<<<dim3(1024), 256, 0, stream>>>(qb, rk, sc);
  qk_gemm<<<dim3(64, 16), 256, 0, stream>>>(qb, kb, sc);
  softmax_kernel<<<dim3(8192), 64, 0, stream>>>(sc, mask, gb);
  relv_kernel<<<dim3(1024), 256, 0, stream>>>(sc, rv, xb);
  pv_gemm<<<dim3(16, 16), 256, 0, stream>>>(sc, vb, xb);
  proj_gemm<0><<<dim3(256), 256, 0, stream>>>(xb, Wo, bo, out);
}

// Round 2
// 312.355 us; speedup vs baseline: 1.5993x; 1.5993x over previous
//
#include <hip/hip_runtime.h>

static constexpr float SCALE = 0.08838834764831845f; // 1/sqrt(128)

typedef __bf16 bf16;
typedef __bf16 bf16x8 __attribute__((ext_vector_type(8)));
typedef float  f32x4  __attribute__((ext_vector_type(4)));

#define MFMA16(a, b, c) __builtin_amdgcn_mfma_f32_16x16x32_bf16((a), (b), (c), 0, 0, 0)

__device__ inline bf16x8 cvt8(const float4& x, const float4& y) {
  bf16x8 r;
  r[0] = (bf16)x.x; r[1] = (bf16)x.y; r[2] = (bf16)x.z; r[3] = (bf16)x.w;
  r[4] = (bf16)y.x; r[5] = (bf16)y.y; r[6] = (bf16)y.z; r[7] = (bf16)y.w;
  return r;
}

// =====================================================================
// proj MFMA GEMM: C = A @ W^T + bias.  A:(1024x1024) f32 row-major,
// W:(1024x1024) f32 row-major (N,K).  fp32->bf16 conversion fused into
// LDS staging; 64x64 tile / 4 waves / wave=32x32 (2x2 MFMA frags).
// LAYOUT 0: Cf[m*1024+n]                       (out-proj)
// LAYOUT 1: Cf + Cb at [((b*8+h)*512+i)*128+dk] (q: fp32 + bf16)
// LAYOUT 2: Cb only at same layout              (k, v: bf16 only)
// =====================================================================
template<int LAYOUT>
__global__ __launch_bounds__(256)
void proj_mfma(const float* __restrict__ A, const float* __restrict__ W,
               const float* __restrict__ bias, float* __restrict__ Cf,
               bf16* __restrict__ Cb)
{
  __shared__ bf16 As[64][72];
  __shared__ bf16 Bs[64][72];
  const int t = threadIdx.x;
  const int m0 = (blockIdx.x >> 4) << 6;
  const int n0 = (blockIdx.x & 15) << 6;
  const int wave = t >> 6, lane = t & 63;
  const int wr = wave >> 1, wc = wave & 1;
  const int srow = t >> 2, skc = (t & 3) << 4;   // 16 floats per thread
  const float* Ap = A + (size_t)(m0 + srow) * 1024 + skc;
  const float* Wp = W + (size_t)(n0 + srow) * 1024 + skc;
  const int fr = lane & 15, kb = (lane >> 4) << 3;
  f32x4 acc[2][2];
#pragma unroll
  for (int i = 0; i < 2; ++i)
#pragma unroll
    for (int j = 0; j < 2; ++j) acc[i][j] = (f32x4){0.f, 0.f, 0.f, 0.f};

  for (int k0 = 0; k0 < 1024; k0 += 64) {
    float4 a4[4], w4[4];
#pragma unroll
    for (int u = 0; u < 4; ++u) {
      a4[u] = *(const float4*)(Ap + k0 + u * 4);
      w4[u] = *(const float4*)(Wp + k0 + u * 4);
    }
    __syncthreads();
    *(bf16x8*)&As[srow][skc]     = cvt8(a4[0], a4[1]);
    *(bf16x8*)&As[srow][skc + 8] = cvt8(a4[2], a4[3]);
    *(bf16x8*)&Bs[srow][skc]     = cvt8(w4[0], w4[1]);
    *(bf16x8*)&Bs[srow][skc + 8] = cvt8(w4[2], w4[3]);
    __syncthreads();
#pragma unroll
    for (int ks = 0; ks < 2; ++ks) {
      bf16x8 af[2], bff[2];
#pragma unroll
      for (int f = 0; f < 2; ++f) {
        af[f]  = *(const bf16x8*)&As[wr * 32 + f * 16 + fr][ks * 32 + kb];
        bff[f] = *(const bf16x8*)&Bs[wc * 32 + f * 16 + fr][ks * 32 + kb];
      }
#pragma unroll
      for (int i = 0; i < 2; ++i)
#pragma unroll
        for (int j = 0; j < 2; ++j)
          acc[i][j] = MFMA16(af[i], bff[j], acc[i][j]);
    }
  }
  const int lrow = (lane >> 4) << 2, lcol = lane & 15;
#pragma unroll
  for (int i = 0; i < 2; ++i) {
#pragma unroll
    for (int j = 0; j < 2; ++j) {
      const int n = n0 + wc * 32 + j * 16 + lcol;
      const float bv = bias[n];
#pragma unroll
      for (int r = 0; r < 4; ++r) {
        const int m = m0 + wr * 32 + i * 16 + lrow + r;
        const float val = acc[i][j][r] + bv;
        if (LAYOUT == 0) {
          Cf[(size_t)m * 1024 + n] = val;
        } else {
          const int b = m >> 9, ii = m & 511, h = n >> 7, dk = n & 127;
          const size_t idx = (((size_t)(b * 8 + h) * 512) + ii) * 128 + dk;
          if (LAYOUT == 1) { Cf[idx] = val; Cb[idx] = (bf16)val; }
          else             { Cb[idx] = (bf16)val; }
        }
      }
    }
  }
}

// =====================================================================
// V transpose: VT[bh][d][i] = V[bh][i][d]  (bf16, 16 x 512 x 128)
// =====================================================================
__global__ __launch_bounds__(256)
void vtrans(const bf16* __restrict__ V, bf16* __restrict__ VT)
{
  const int bh = blockIdx.y;
  const int it = blockIdx.x >> 1, dt = blockIdx.x & 1;
  __shared__ bf16 T[64][72];
  const int t = threadIdx.x;
  const int r = t >> 2, c = (t & 3) << 4;
  const bf16* src = V + ((size_t)bh * 512 + it * 64 + r) * 128 + dt * 64 + c;
  uint4 v0 = *(const uint4*)src;
  uint4 v1 = *(const uint4*)(src + 8);
  *(uint4*)&T[r][c]     = v0;
  *(uint4*)&T[r][c + 8] = v1;
  __syncthreads();
  bf16 tmp[16];
#pragma unroll
  for (int u = 0; u < 16; ++u) tmp[u] = T[c + u][r];
  bf16* dst = VT + ((size_t)bh * 128 + dt * 64 + r) * 512 + it * 64 + c;
  *(uint4*)dst       = *(uint4*)&tmp[0];
  *(uint4*)(dst + 8) = *(uint4*)&tmp[8];
}

// =====================================================================
// QK^T MFMA: scores[bh] += q16[bh] @ k16[bh]^T  (M=N=512, K=128, bf16)
// =====================================================================
__global__ __launch_bounds__(256)
void qk_mfma(const bf16* __restrict__ Q, const bf16* __restrict__ Kb,
             float* __restrict__ scores)
{
  const int bh = blockIdx.y;
  const bf16* A = Q  + (size_t)bh * (512 * 128);
  const bf16* B = Kb + (size_t)bh * (512 * 128);
  float* C = scores + (size_t)bh * (512 * 512);
  const int m0 = (blockIdx.x >> 3) << 6, n0 = (blockIdx.x & 7) << 6;
  __shared__ bf16 As[64][72];
  __shared__ bf16 Bs[64][72];
  const int t = threadIdx.x, wave = t >> 6, lane = t & 63;
  const int wr = wave >> 1, wc = wave & 1;
  const int srow = t >> 2, skc = (t & 3) << 4;
  const int fr = lane & 15, kb = (lane >> 4) << 3;
  f32x4 acc[2][2];
#pragma unroll
  for (int i = 0; i < 2; ++i)
#pragma unroll
    for (int j = 0; j < 2; ++j) acc[i][j] = (f32x4){0.f, 0.f, 0.f, 0.f};

  for (int k0 = 0; k0 < 128; k0 += 64) {
    const bf16* ap = A + (size_t)(m0 + srow) * 128 + k0 + skc;
    const bf16* bp = B + (size_t)(n0 + srow) * 128 + k0 + skc;
    uint4 a0 = *(const uint4*)ap;
    uint4 a1 = *(const uint4*)(ap + 8);
    uint4 b0 = *(const uint4*)bp;
    uint4 b1 = *(const uint4*)(bp + 8);
    __syncthreads();
    *(uint4*)&As[srow][skc]     = a0; *(uint4*)&As[srow][skc + 8] = a1;
    *(uint4*)&Bs[srow][skc]     = b0; *(uint4*)&Bs[srow][skc + 8] = b1;
    __syncthreads();
#pragma unroll
    for (int ks = 0; ks < 2; ++ks) {
      bf16x8 af[2], bff[2];
#pragma unroll
      for (int f = 0; f < 2; ++f) {
        af[f]  = *(const bf16x8*)&As[wr * 32 + f * 16 + fr][ks * 32 + kb];
        bff[f] = *(const bf16x8*)&Bs[wc * 32 + f * 16 + fr][ks * 32 + kb];
      }
#pragma unroll
      for (int i = 0; i < 2; ++i)
#pragma unroll
        for (int j = 0; j < 2; ++j)
          acc[i][j] = MFMA16(af[i], bff[j], acc[i][j]);
    }
  }
  const int lrow = (lane >> 4) << 2, lcol = lane & 15;
#pragma unroll
  for (int i = 0; i < 2; ++i)
#pragma unroll
    for (int j = 0; j < 2; ++j)
#pragma unroll
      for (int r = 0; r < 4; ++r) {
        const int m = m0 + wr * 32 + i * 16 + lrow + r;
        const int n = n0 + wc * 32 + j * 16 + lcol;
        C[(size_t)m * 512 + n] += acc[i][j][r];
      }
}

// =====================================================================
// PV MFMA: x[b,i,h*128+n] += p16[bh] @ vt16[bh]^T-form
// A: p16 (bh,512,512) bf16; B(W-form): vt16 (bh,128,512) bf16
// =====================================================================
__global__ __launch_bounds__(256)
void pv_mfma(const bf16* __restrict__ P, const bf16* __restrict__ VT,
             float* __restrict__ x)
{
  const int bh = blockIdx.y, b = bh >> 3, h = bh & 7;
  const bf16* A = P  + (size_t)bh * (512 * 512);
  const bf16* B = VT + (size_t)bh * (128 * 512);
  float* C = x + (size_t)b * (512 * 1024) + h * 128;
  const int m0 = (blockIdx.x >> 1) << 6, n0 = (blockIdx.x & 1) << 6;
  __shared__ bf16 As[64][72];
  __shared__ bf16 Bs[64][72];
  const int t = threadIdx.x, wave = t >> 6, lane = t & 63;
  const int wr = wave >> 1, wc = wave & 1;
  const int srow = t >> 2, skc = (t & 3) << 4;
  const int fr = lane & 15, kb = (lane >> 4) << 3;
  f32x4 acc[2][2];
#pragma unroll
  for (int i = 0; i < 2; ++i)
#pragma unroll
    for (int j = 0; j < 2; ++j) acc[i][j] = (f32x4){0.f, 0.f, 0.f, 0.f};

  for (int k0 = 0; k0 < 512; k0 += 64) {
    const bf16* ap = A + (size_t)(m0 + srow) * 512 + k0 + skc;
    const bf16* bp = B + (size_t)(n0 + srow) * 512 + k0 + skc;
    uint4 a0 = *(const uint4*)ap;
    uint4 a1 = *(const uint4*)(ap + 8);
    uint4 b0 = *(const uint4*)bp;
    uint4 b1 = *(const uint4*)(bp + 8);
    __syncthreads();
    *(uint4*)&As[srow][skc]     = a0; *(uint4*)&As[srow][skc + 8] = a1;
    *(uint4*)&Bs[srow][skc]     = b0; *(uint4*)&Bs[srow][skc + 8] = b1;
    __syncthreads();
#pragma unroll
    for (int ks = 0; ks < 2; ++ks) {
      bf16x8 af[2], bff[2];
#pragma unroll
      for (int f = 0; f < 2; ++f) {
        af[f]  = *(const bf16x8*)&As[wr * 32 + f * 16 + fr][ks * 32 + kb];
        bff[f] = *(const bf16x8*)&Bs[wc * 32 + f * 16 + fr][ks * 32 + kb];
      }
#pragma unroll
      for (int i = 0; i < 2; ++i)
#pragma unroll
        for (int j = 0; j < 2; ++j)
          acc[i][j] = MFMA16(af[i], bff[j], acc[i][j]);
    }
  }
  const int lrow = (lane >> 4) << 2, lcol = lane & 15;
#pragma unroll
  for (int i = 0; i < 2; ++i)
#pragma unroll
    for (int j = 0; j < 2; ++j)
#pragma unroll
      for (int r = 0; r < 4; ++r) {
        const int m = m0 + wr * 32 + i * 16 + lrow + r;
        const int n = n0 + wc * 32 + j * 16 + lcol;
        C[(size_t)m * 1024 + n] += acc[i][j][r];
      }
}

// =====================================================================
// relation_k kernel: per (b,i) block, streams rk[b,i,:,:] (256 KB) and
// writes scores[b,h,i,j] = q[b,h,i,:] . rk[b,i,j,:]   (raw, unscaled)
// =====================================================================
__global__ __launch_bounds__(256)
void relk_kernel(const float* __restrict__ qb, const float* __restrict__ rk,
                 float* __restrict__ scores)
{
  const int bi = blockIdx.x;
  const int b = bi >> 9, i = bi & 511;
  __shared__ float qs[8][144];
  const int t = threadIdx.x;
  {
    const int h = t >> 5, d0 = (t & 31) << 2;
    const int sub = d0 >> 5, dd = d0 & 31;
    const float4 qv = *(const float4*)&qb[(((size_t)(b * 8 + h) * 512) + i) * 128 + d0];
    *(float4*)&qs[h][sub * 36 + dd] = qv;
  }
  __syncthreads();
  const int jj = t >> 2, sub = t & 3;
  for (int jp = 0; jp < 512; jp += 64) {
    const int j = jp + jj;
    const float* rkp = rk + ((size_t)bi * 512 + j) * 128 + sub * 32;
    float rvl[32];
#pragma unroll
    for (int u = 0; u < 8; ++u)
      *(float4*)&rvl[u * 4] = *(const float4*)&rkp[u * 4];
    float acc[8];
#pragma unroll
    for (int h = 0; h < 8; ++h) acc[h] = 0.f;
#pragma unroll
    for (int d4 = 0; d4 < 8; ++d4) {
#pragma unroll
      for (int h = 0; h < 8; ++h) {
        const float4 qv = *(const float4*)&qs[h][sub * 36 + (d4 << 2)];
        acc[h] = fmaf(qv.x, rvl[d4*4+0], acc[h]);
        acc[h] = fmaf(qv.y, rvl[d4*4+1], acc[h]);
        acc[h] = fmaf(qv.z, rvl[d4*4+2], acc[h]);
        acc[h] = fmaf(qv.w, rvl[d4*4+3], acc[h]);
      }
    }
#pragma unroll
    for (int h = 0; h < 8; ++h) {
      acc[h] += __shfl_xor(acc[h], 1);
      acc[h] += __shfl_xor(acc[h], 2);
    }
    const int h0 = sub << 1;
    scores[(((size_t)(b*8 + h0  ) * 512) + i) * 512 + j] = acc[h0];
    scores[(((size_t)(b*8 + h0+1) * 512) + i) * 512 + j] = acc[h0+1];
  }
}

// =====================================================================
// relation_v kernel: per (b,i) block, streams rv[b,i,:,:] and writes
// x[b,i,h*128+d] = sum_j p[b,h,i,j]*rv[b,i,j,d]
// =====================================================================
__global__ __launch_bounds__(256)
void relv_kernel(const float* __restrict__ p, const float* __restrict__ rvg,
                 float* __restrict__ x)
{
  const int bi = blockIdx.x, b = bi >> 9, i = bi & 511;
  __shared__ float ps[8][512];
  const int t = threadIdx.x;
  for (int i4 = t; i4 < 1024; i4 += 256) {
    const int h = i4 >> 7, j0 = (i4 & 127) << 2;
    *(float4*)&ps[h][j0] =
        *(const float4*)&p[(((size_t)(b*8 + h) * 512) + i) * 512 + j0];
  }
  __syncthreads();
  const int h = t >> 5, d0 = (t & 31) << 2;
  const float* rp = rvg + (size_t)bi * 512 * 128 + d0;
  float4 acc = make_float4(0.f, 0.f, 0.f, 0.f);
  for (int j = 0; j < 512; j += 8) {
    float4 rr[8];
#pragma unroll
    for (int u = 0; u < 8; ++u)
      rr[u] = *(const float4*)&rp[(size_t)(j + u) * 128];
#pragma unroll
    for (int u = 0; u < 8; ++u) {
      const float w = ps[h][j + u];
      acc.x = fmaf(w, rr[u].x, acc.x);
      acc.y = fmaf(w, rr[u].y, acc.y);
      acc.z = fmaf(w, rr[u].z, acc.z);
      acc.w = fmaf(w, rr[u].w, acc.w);
    }
  }
  *(float4*)&x[((size_t)(b * 512 + i)) * 1024 + h * 128 + d0] = acc;
}

// =====================================================================
// sep / gating / loss kernel (single block).
// =====================================================================
__global__ __launch_bounds__(256)
void sep_kernel(const float* __restrict__ qb, const float* __restrict__ hw,
                const int* __restrict__ sep_id, const float* __restrict__ hreg,
                float* __restrict__ g, float* __restrict__ loss_out)
{
  __shared__ float pool[16][4];
  __shared__ float spred[16][4];
  __shared__ float lbuf[16];
  __shared__ int sids[4];
  const int t = threadIdx.x;
  if (t < 4) sids[t] = sep_id[t];
  __syncthreads();
  {
    const int dot = t >> 2, sub = t & 3;
    const int bh = dot >> 2, n = dot & 3;
    const int b = bh >> 3, h = bh & 7;
    const int row = sids[n];
    const float* qp = qb + (((size_t)(b * 8 + h) * 512) + row) * 128 + sub * 32;
    const float* wp = hw + h * 128 + sub * 32;
    float s = 0.f;
#pragma unroll
    for (int dd = 0; dd < 32; ++dd) s = fmaf(qp[dd], wp[dd], s);
    s += __shfl_xor(s, 1);
    s += __shfl_xor(s, 2);
    if (sub == 0) { pool[bh][n] = s; }
  }
  __syncthreads();
  if (t < 16) {
    float pv[4];
#pragma unroll
    for (int n = 0; n < 4; ++n) pv[n] = pool[t][n];
    float mx = fmaxf(fmaxf(pv[0], pv[1]), fmaxf(pv[2], pv[3]));
    float sum = 0.f;
#pragma unroll
    for (int n = 0; n < 4; ++n) { pv[n] = expf(pv[n] - mx); sum += pv[n]; }
    const float inv = 1.f / sum;
    float maxp = 0.f, l2 = 0.f;
#pragma unroll
    for (int n = 0; n < 4; ++n) {
      const float pr = pv[n] * inv;
      spred[t][n] = pr;
      maxp = fmaxf(maxp, pr);
      const float tg = hreg[n];
      l2 += tg * (logf(tg) - logf(pr));
    }
    lbuf[t] = (1.f - maxp) / 16.f + l2 / 64.f;
  }
  __syncthreads();
  if (t == 0) {
    float L = 0.f;
#pragma unroll
    for (int r = 0; r < 16; ++r) L += lbuf[r];
    loss_out[0] = L;
  }
  for (int idx = t; idx < 16 * 512; idx += 256) {
    const int bh = idx >> 9, pp = idx & 511;
    float gg = 0.f;
#pragma unroll
    for (int n = 0; n < 4; ++n)
      gg += spred[bh][n] * (pp >= sids[n] ? 1.f : 0.f);
    g[idx] = gg;
  }
}

// =====================================================================
// softmax kernel: one wave per (b,h,i) row; writes fp32 in-place (for
// relv) and a bf16 copy (for pv_mfma).
// =====================================================================
__global__ __launch_bounds__(64)
void softmax_kernel(float* __restrict__ scores, const int* __restrict__ mask,
                    const float* __restrict__ g, bf16* __restrict__ pb)
{
  const int bhi = blockIdx.x;
  const int i = bhi & 511;
  const int bh = bhi >> 9;
  const int b = bh >> 3;
  float* row = scores + (size_t)bhi * 512;
  const int* mrow = mask + ((size_t)(b * 512 + i)) * 512;
  const float* grow = g + bh * 512;
  const float gi = grow[i];
  const int j0 = threadIdx.x << 3;
  float va[8];
  *(float4*)&va[0] = *(const float4*)&row[j0];
  *(float4*)&va[4] = *(const float4*)&row[j0 + 4];
  int ma[8];
  *(int4*)&ma[0] = *(const int4*)&mrow[j0];
  *(int4*)&ma[4] = *(const int4*)&mrow[j0 + 4];
  float ga[8];
  *(float4*)&ga[0] = *(const float4*)&grow[j0];
  *(float4*)&ga[4] = *(const float4*)&grow[j0 + 4];
  float mx = -3.402823466e+38f;
#pragma unroll
  for (int u = 0; u < 8; ++u) {
    const int j = j0 + u;
    float s = va[u] * SCALE;
    if (ma[u] == 0) s = -1.0e9f;
    const float fac = (j >= i) ? gi : ga[u];
    s *= fac;
    va[u] = s;
    mx = fmaxf(mx, s);
  }
#pragma unroll
  for (int off = 32; off > 0; off >>= 1) mx = fmaxf(mx, __shfl_xor(mx, off));
  float sum = 0.f;
#pragma unroll
  for (int u = 0; u < 8; ++u) { const float e = __expf(va[u] - mx); va[u] = e; sum += e; }
#pragma unroll
  for (int off = 32; off > 0; off >>= 1) sum += __shfl_xor(sum, off);
  const float inv = 1.f / sum;
  bf16 pb8[8];
#pragma unroll
  for (int u = 0; u < 8; ++u) { va[u] *= inv; pb8[u] = (bf16)va[u]; }
  *(float4*)&row[j0]     = *(const float4*)&va[0];
  *(float4*)&row[j0 + 4] = *(const float4*)&va[4];
  *(uint4*)&pb[(size_t)bhi * 512 + j0] = *(uint4*)&pb8[0];
}

// =====================================================================
extern "C" void kernel_launch(void* const* d_in, const int* in_sizes, int n_in,
                              void* d_out, int out_size, void* d_ws, size_t ws_size,
                              hipStream_t stream)
{
  const float* query = (const float*)d_in[0];
  const float* key   = (const float*)d_in[1];
  const float* value = (const float*)d_in[2];
  const float* rk    = (const float*)d_in[3];
  const float* rv    = (const float*)d_in[4];
  const int*   mask  = (const int*)d_in[5];
  const int*   sep   = (const int*)d_in[6];
  const float* hreg  = (const float*)d_in[7];
  const float* Wq    = (const float*)d_in[8];
  const float* bq    = (const float*)d_in[9];
  const float* Wk    = (const float*)d_in[10];
  const float* bk    = (const float*)d_in[11];
  const float* Wv    = (const float*)d_in[12];
  const float* bv    = (const float*)d_in[13];
  const float* Wo    = (const float*)d_in[14];
  const float* bo    = (const float*)d_in[15];
  const float* hw    = (const float*)d_in[16];
  float* out = (float*)d_out;

  float* ws = (float*)d_ws;
  float* qb  = ws;                 // 1,048,576 f32
  float* sc  = qb  + 1048576;      // 4,194,304 f32
  float* xb  = sc  + 4194304;      // 1,048,576 f32
  float* gb  = xb  + 1048576;      //     8,192 f32
  bf16* qb16 = (bf16*)(gb + 8192);           // 1,048,576 bf16
  bf16* kb16 = qb16 + 1048576;               // 1,048,576 bf16
  bf16* vb16 = kb16 + 1048576;               // 1,048,576 bf16
  bf16* vt16 = vb16 + 1048576;               // 1,048,576 bf16
  bf16* pb16 = vt16 + 1048576;               // 4,194,304 bf16
  // total ~40 MB

  proj_mfma<1><<<dim3(256), 256, 0, stream>>>(query, Wq, bq, qb, qb16);
  proj_mfma<2><<<dim3(256), 256, 0, stream>>>(key,   Wk, bk, nullptr, kb16);
  proj_mfma<2><<<dim3(256), 256, 0, stream>>>(value, Wv, bv, nullptr, vb16);
  vtrans<<<dim3(16, 16), 256, 0, stream>>>(vb16, vt16);
  sep_kernel<<<dim3(1), 256, 0, stream>>>(qb, hw, sep, hreg, gb, out + 1048576);
  relk_kernel<<<dim3(1024), 256, 0, stream>>>(qb, rk, sc);
  qk_mfma<<<dim3(64, 16), 256, 0, stream>>>(qb16, kb16, sc);
  softmax_kernel<<<dim3(8192), 64, 0, stream>>>(sc, mask, gb, pb16);
  relv_kernel<<<dim3(1024), 256, 0, stream>>>(sc, rv, xb);
  pv_mfma<<<dim3(16, 16), 256, 0, stream>>>(pb16, vt16, xb);
  proj_mfma<0><<<dim3(256), 256, 0, stream>>>(xb, Wo, bo, out, nullptr);
}

// Round 3
// 273.124 us; speedup vs baseline: 1.8290x; 1.1436x over previous
//
#include <hip/hip_runtime.h>

static constexpr float SCALE = 0.08838834764831845f; // 1/sqrt(128)

typedef __bf16 bf16;
typedef __bf16 bf16x8 __attribute__((ext_vector_type(8)));
typedef float  f32x4  __attribute__((ext_vector_type(4)));

#define MFMA16(a, b, c) __builtin_amdgcn_mfma_f32_16x16x32_bf16((a), (b), (c), 0, 0, 0)

__device__ inline bf16x8 cvt8(const float4& x, const float4& y) {
  bf16x8 r;
  r[0] = (bf16)x.x; r[1] = (bf16)x.y; r[2] = (bf16)x.z; r[3] = (bf16)x.w;
  r[4] = (bf16)y.x; r[5] = (bf16)y.y; r[6] = (bf16)y.z; r[7] = (bf16)y.w;
  return r;
}

// =====================================================================
// Batched projection GEMM (q,k,v in one launch; blockIdx.y selects).
// C = A @ W^T + bias.  A:(1024x1024) f32, W:(1024x1024) f32 (N,K).
// 64x64 tile, 4 waves, wave = 32x32 (2x2 MFMA frags), register
// double-buffer prefetch on the K loop.
// sel==0 (q): write fp32 Cf + bf16 Cb; sel>0 (k,v): bf16 only.
// Output layout: [((b*8+h)*512+i)*128+dk]
// =====================================================================
__global__ __launch_bounds__(256)
void proj3_mfma(const float* __restrict__ Aq, const float* __restrict__ Ak,
                const float* __restrict__ Av,
                const float* __restrict__ Wq, const float* __restrict__ Wk,
                const float* __restrict__ Wv,
                const float* __restrict__ bq, const float* __restrict__ bk,
                const float* __restrict__ bv,
                float* __restrict__ qf,
                bf16* __restrict__ q16, bf16* __restrict__ k16,
                bf16* __restrict__ v16)
{
  const int sel = blockIdx.y;
  const float* A    = sel == 0 ? Aq : (sel == 1 ? Ak : Av);
  const float* W    = sel == 0 ? Wq : (sel == 1 ? Wk : Wv);
  const float* bias = sel == 0 ? bq : (sel == 1 ? bk : bv);
  bf16* Cb          = sel == 0 ? q16 : (sel == 1 ? k16 : v16);

  __shared__ bf16 As[64][72];
  __shared__ bf16 Bs[64][72];
  const int t = threadIdx.x;
  const int m0 = (blockIdx.x >> 4) << 6;
  const int n0 = (blockIdx.x & 15) << 6;
  const int wave = t >> 6, lane = t & 63;
  const int wr = wave >> 1, wc = wave & 1;
  const int srow = t >> 2, skc = (t & 3) << 4;
  const float* Ap = A + (size_t)(m0 + srow) * 1024 + skc;
  const float* Wp = W + (size_t)(n0 + srow) * 1024 + skc;
  const int fr = lane & 15, kb = (lane >> 4) << 3;
  f32x4 acc[2][2];
#pragma unroll
  for (int i = 0; i < 2; ++i)
#pragma unroll
    for (int j = 0; j < 2; ++j) acc[i][j] = (f32x4){0.f, 0.f, 0.f, 0.f};

  float4 a4[4], w4[4], a4n[4], w4n[4];
#pragma unroll
  for (int u = 0; u < 4; ++u) {
    a4[u] = *(const float4*)(Ap + u * 4);
    w4[u] = *(const float4*)(Wp + u * 4);
  }
  for (int k0 = 0; k0 < 1024; k0 += 64) {
    __syncthreads();
    *(bf16x8*)&As[srow][skc]     = cvt8(a4[0], a4[1]);
    *(bf16x8*)&As[srow][skc + 8] = cvt8(a4[2], a4[3]);
    *(bf16x8*)&Bs[srow][skc]     = cvt8(w4[0], w4[1]);
    *(bf16x8*)&Bs[srow][skc + 8] = cvt8(w4[2], w4[3]);
    __syncthreads();
    if (k0 + 64 < 1024) {
#pragma unroll
      for (int u = 0; u < 4; ++u) {
        a4n[u] = *(const float4*)(Ap + k0 + 64 + u * 4);
        w4n[u] = *(const float4*)(Wp + k0 + 64 + u * 4);
      }
    }
#pragma unroll
    for (int ks = 0; ks < 2; ++ks) {
      bf16x8 af[2], bff[2];
#pragma unroll
      for (int f = 0; f < 2; ++f) {
        af[f]  = *(const bf16x8*)&As[wr * 32 + f * 16 + fr][ks * 32 + kb];
        bff[f] = *(const bf16x8*)&Bs[wc * 32 + f * 16 + fr][ks * 32 + kb];
      }
#pragma unroll
      for (int i = 0; i < 2; ++i)
#pragma unroll
        for (int j = 0; j < 2; ++j)
          acc[i][j] = MFMA16(af[i], bff[j], acc[i][j]);
    }
#pragma unroll
    for (int u = 0; u < 4; ++u) { a4[u] = a4n[u]; w4[u] = w4n[u]; }
  }
  const int lrow = (lane >> 4) << 2, lcol = lane & 15;
#pragma unroll
  for (int i = 0; i < 2; ++i) {
#pragma unroll
    for (int j = 0; j < 2; ++j) {
      const int n = n0 + wc * 32 + j * 16 + lcol;
      const float bvl = bias[n];
#pragma unroll
      for (int r = 0; r < 4; ++r) {
        const int m = m0 + wr * 32 + i * 16 + lrow + r;
        const float val = acc[i][j][r] + bvl;
        const int b = m >> 9, ii = m & 511, h = n >> 7, dk = n & 127;
        const size_t idx = (((size_t)(b * 8 + h) * 512) + ii) * 128 + dk;
        Cb[idx] = (bf16)val;
        if (sel == 0) qf[idx] = val;
      }
    }
  }
}

// =====================================================================
// Output projection: Cf[m*1024+n] = A @ W^T + bias (A = xb fp32)
// =====================================================================
__global__ __launch_bounds__(256)
void proj_out(const float* __restrict__ A, const float* __restrict__ W,
              const float* __restrict__ bias, float* __restrict__ Cf)
{
  __shared__ bf16 As[64][72];
  __shared__ bf16 Bs[64][72];
  const int t = threadIdx.x;
  const int m0 = (blockIdx.x >> 4) << 6;
  const int n0 = (blockIdx.x & 15) << 6;
  const int wave = t >> 6, lane = t & 63;
  const int wr = wave >> 1, wc = wave & 1;
  const int srow = t >> 2, skc = (t & 3) << 4;
  const float* Ap = A + (size_t)(m0 + srow) * 1024 + skc;
  const float* Wp = W + (size_t)(n0 + srow) * 1024 + skc;
  const int fr = lane & 15, kb = (lane >> 4) << 3;
  f32x4 acc[2][2];
#pragma unroll
  for (int i = 0; i < 2; ++i)
#pragma unroll
    for (int j = 0; j < 2; ++j) acc[i][j] = (f32x4){0.f, 0.f, 0.f, 0.f};

  float4 a4[4], w4[4], a4n[4], w4n[4];
#pragma unroll
  for (int u = 0; u < 4; ++u) {
    a4[u] = *(const float4*)(Ap + u * 4);
    w4[u] = *(const float4*)(Wp + u * 4);
  }
  for (int k0 = 0; k0 < 1024; k0 += 64) {
    __syncthreads();
    *(bf16x8*)&As[srow][skc]     = cvt8(a4[0], a4[1]);
    *(bf16x8*)&As[srow][skc + 8] = cvt8(a4[2], a4[3]);
    *(bf16x8*)&Bs[srow][skc]     = cvt8(w4[0], w4[1]);
    *(bf16x8*)&Bs[srow][skc + 8] = cvt8(w4[2], w4[3]);
    __syncthreads();
    if (k0 + 64 < 1024) {
#pragma unroll
      for (int u = 0; u < 4; ++u) {
        a4n[u] = *(const float4*)(Ap + k0 + 64 + u * 4);
        w4n[u] = *(const float4*)(Wp + k0 + 64 + u * 4);
      }
    }
#pragma unroll
    for (int ks = 0; ks < 2; ++ks) {
      bf16x8 af[2], bff[2];
#pragma unroll
      for (int f = 0; f < 2; ++f) {
        af[f]  = *(const bf16x8*)&As[wr * 32 + f * 16 + fr][ks * 32 + kb];
        bff[f] = *(const bf16x8*)&Bs[wc * 32 + f * 16 + fr][ks * 32 + kb];
      }
#pragma unroll
      for (int i = 0; i < 2; ++i)
#pragma unroll
        for (int j = 0; j < 2; ++j)
          acc[i][j] = MFMA16(af[i], bff[j], acc[i][j]);
    }
#pragma unroll
    for (int u = 0; u < 4; ++u) { a4[u] = a4n[u]; w4[u] = w4n[u]; }
  }
  const int lrow = (lane >> 4) << 2, lcol = lane & 15;
#pragma unroll
  for (int i = 0; i < 2; ++i) {
#pragma unroll
    for (int j = 0; j < 2; ++j) {
      const int n = n0 + wc * 32 + j * 16 + lcol;
      const float bvl = bias[n];
#pragma unroll
      for (int r = 0; r < 4; ++r) {
        const int m = m0 + wr * 32 + i * 16 + lrow + r;
        Cf[(size_t)m * 1024 + n] = acc[i][j][r] + bvl;
      }
    }
  }
}

// =====================================================================
// V transpose: VT[bh][d][i] = V[bh][i][d]  (bf16, 16 x 512 x 128)
// =====================================================================
__global__ __launch_bounds__(256)
void vtrans(const bf16* __restrict__ V, bf16* __restrict__ VT)
{
  const int bh = blockIdx.y;
  const int it = blockIdx.x >> 1, dt = blockIdx.x & 1;
  __shared__ bf16 T[64][72];
  const int t = threadIdx.x;
  const int r = t >> 2, c = (t & 3) << 4;
  const bf16* src = V + ((size_t)bh * 512 + it * 64 + r) * 128 + dt * 64 + c;
  uint4 v0 = *(const uint4*)src;
  uint4 v1 = *(const uint4*)(src + 8);
  *(uint4*)&T[r][c]     = v0;
  *(uint4*)&T[r][c + 8] = v1;
  __syncthreads();
  bf16 tmp[16];
#pragma unroll
  for (int u = 0; u < 16; ++u) tmp[u] = T[c + u][r];
  bf16* dst = VT + ((size_t)bh * 128 + dt * 64 + r) * 512 + it * 64 + c;
  *(uint4*)dst       = *(uint4*)&tmp[0];
  *(uint4*)(dst + 8) = *(uint4*)&tmp[8];
}

// =====================================================================
// QK^T MFMA: scores[bh] += q16[bh] @ k16[bh]^T  (M=N=512, K=128, bf16)
// =====================================================================
__global__ __launch_bounds__(256)
void qk_mfma(const bf16* __restrict__ Q, const bf16* __restrict__ Kb,
             float* __restrict__ scores)
{
  const int bh = blockIdx.y;
  const bf16* A = Q  + (size_t)bh * (512 * 128);
  const bf16* B = Kb + (size_t)bh * (512 * 128);
  float* C = scores + (size_t)bh * (512 * 512);
  const int m0 = (blockIdx.x >> 3) << 6, n0 = (blockIdx.x & 7) << 6;
  __shared__ bf16 As[64][72];
  __shared__ bf16 Bs[64][72];
  const int t = threadIdx.x, wave = t >> 6, lane = t & 63;
  const int wr = wave >> 1, wc = wave & 1;
  const int srow = t >> 2, skc = (t & 3) << 4;
  const int fr = lane & 15, kb = (lane >> 4) << 3;
  f32x4 acc[2][2];
#pragma unroll
  for (int i = 0; i < 2; ++i)
#pragma unroll
    for (int j = 0; j < 2; ++j) acc[i][j] = (f32x4){0.f, 0.f, 0.f, 0.f};

  const bf16* ap = A + (size_t)(m0 + srow) * 128 + skc;
  const bf16* bp = B + (size_t)(n0 + srow) * 128 + skc;
  uint4 a0 = *(const uint4*)ap, a1 = *(const uint4*)(ap + 8);
  uint4 b0 = *(const uint4*)bp, b1 = *(const uint4*)(bp + 8);
  for (int k0 = 0; k0 < 128; k0 += 64) {
    __syncthreads();
    *(uint4*)&As[srow][skc]     = a0; *(uint4*)&As[srow][skc + 8] = a1;
    *(uint4*)&Bs[srow][skc]     = b0; *(uint4*)&Bs[srow][skc + 8] = b1;
    __syncthreads();
    if (k0 == 0) {
      a0 = *(const uint4*)(ap + 64); a1 = *(const uint4*)(ap + 72);
      b0 = *(const uint4*)(bp + 64); b1 = *(const uint4*)(bp + 72);
    }
#pragma unroll
    for (int ks = 0; ks < 2; ++ks) {
      bf16x8 af[2], bff[2];
#pragma unroll
      for (int f = 0; f < 2; ++f) {
        af[f]  = *(const bf16x8*)&As[wr * 32 + f * 16 + fr][ks * 32 + kb];
        bff[f] = *(const bf16x8*)&Bs[wc * 32 + f * 16 + fr][ks * 32 + kb];
      }
#pragma unroll
      for (int i = 0; i < 2; ++i)
#pragma unroll
        for (int j = 0; j < 2; ++j)
          acc[i][j] = MFMA16(af[i], bff[j], acc[i][j]);
    }
  }
  const int lrow = (lane >> 4) << 2, lcol = lane & 15;
#pragma unroll
  for (int i = 0; i < 2; ++i)
#pragma unroll
    for (int j = 0; j < 2; ++j)
#pragma unroll
      for (int r = 0; r < 4; ++r) {
        const int m = m0 + wr * 32 + i * 16 + lrow + r;
        const int n = n0 + wc * 32 + j * 16 + lcol;
        C[(size_t)m * 512 + n] += acc[i][j][r];
      }
}

// =====================================================================
// PV MFMA: x[b,i,h*128+n] += p16[bh] @ vt16[bh] (W-form, K=512)
// =====================================================================
__global__ __launch_bounds__(256)
void pv_mfma(const bf16* __restrict__ P, const bf16* __restrict__ VT,
             float* __restrict__ x)
{
  const int bh = blockIdx.y, b = bh >> 3, h = bh & 7;
  const bf16* A = P  + (size_t)bh * (512 * 512);
  const bf16* B = VT + (size_t)bh * (128 * 512);
  float* C = x + (size_t)b * (512 * 1024) + h * 128;
  const int m0 = (blockIdx.x >> 1) << 6, n0 = (blockIdx.x & 1) << 6;
  __shared__ bf16 As[64][72];
  __shared__ bf16 Bs[64][72];
  const int t = threadIdx.x, wave = t >> 6, lane = t & 63;
  const int wr = wave >> 1, wc = wave & 1;
  const int srow = t >> 2, skc = (t & 3) << 4;
  const int fr = lane & 15, kb = (lane >> 4) << 3;
  f32x4 acc[2][2];
#pragma unroll
  for (int i = 0; i < 2; ++i)
#pragma unroll
    for (int j = 0; j < 2; ++j) acc[i][j] = (f32x4){0.f, 0.f, 0.f, 0.f};

  const bf16* ap = A + (size_t)(m0 + srow) * 512 + skc;
  const bf16* bp = B + (size_t)(n0 + srow) * 512 + skc;
  uint4 a0 = *(const uint4*)ap, a1 = *(const uint4*)(ap + 8);
  uint4 b0 = *(const uint4*)bp, b1 = *(const uint4*)(bp + 8);
  for (int k0 = 0; k0 < 512; k0 += 64) {
    __syncthreads();
    *(uint4*)&As[srow][skc]     = a0; *(uint4*)&As[srow][skc + 8] = a1;
    *(uint4*)&Bs[srow][skc]     = b0; *(uint4*)&Bs[srow][skc + 8] = b1;
    __syncthreads();
    if (k0 + 64 < 512) {
      a0 = *(const uint4*)(ap + k0 + 64); a1 = *(const uint4*)(ap + k0 + 72);
      b0 = *(const uint4*)(bp + k0 + 64); b1 = *(const uint4*)(bp + k0 + 72);
    }
#pragma unroll
    for (int ks = 0; ks < 2; ++ks) {
      bf16x8 af[2], bff[2];
#pragma unroll
      for (int f = 0; f < 2; ++f) {
        af[f]  = *(const bf16x8*)&As[wr * 32 + f * 16 + fr][ks * 32 + kb];
        bff[f] = *(const bf16x8*)&Bs[wc * 32 + f * 16 + fr][ks * 32 + kb];
      }
#pragma unroll
      for (int i = 0; i < 2; ++i)
#pragma unroll
        for (int j = 0; j < 2; ++j)
          acc[i][j] = MFMA16(af[i], bff[j], acc[i][j]);
    }
  }
  const int lrow = (lane >> 4) << 2, lcol = lane & 15;
#pragma unroll
  for (int i = 0; i < 2; ++i)
#pragma unroll
    for (int j = 0; j < 2; ++j)
#pragma unroll
      for (int r = 0; r < 4; ++r) {
        const int m = m0 + wr * 32 + i * 16 + lrow + r;
        const int n = n0 + wc * 32 + j * 16 + lcol;
        C[(size_t)m * 1024 + n] += acc[i][j][r];
      }
}

// =====================================================================
// relation_k kernel: per (b,i) block, streams rk[b,i,:,:] (256 KB) and
// writes scores[b,h,i,j] = q[b,h,i,:] . rk[b,i,j,:]   (raw, unscaled)
// =====================================================================
__global__ __launch_bounds__(256)
void relk_kernel(const float* __restrict__ qb, const float* __restrict__ rk,
                 float* __restrict__ scores)
{
  const int bi = blockIdx.x;
  const int b = bi >> 9, i = bi & 511;
  __shared__ float qs[8][144];
  const int t = threadIdx.x;
  {
    const int h = t >> 5, d0 = (t & 31) << 2;
    const int sub = d0 >> 5, dd = d0 & 31;
    const float4 qv = *(const float4*)&qb[(((size_t)(b * 8 + h) * 512) + i) * 128 + d0];
    *(float4*)&qs[h][sub * 36 + dd] = qv;
  }
  __syncthreads();
  const int jj = t >> 2, sub = t & 3;
  for (int jp = 0; jp < 512; jp += 64) {
    const int j = jp + jj;
    const float* rkp = rk + ((size_t)bi * 512 + j) * 128 + sub * 32;
    float rvl[32];
#pragma unroll
    for (int u = 0; u < 8; ++u)
      *(float4*)&rvl[u * 4] = *(const float4*)&rkp[u * 4];
    float acc[8];
#pragma unroll
    for (int h = 0; h < 8; ++h) acc[h] = 0.f;
#pragma unroll
    for (int d4 = 0; d4 < 8; ++d4) {
#pragma unroll
      for (int h = 0; h < 8; ++h) {
        const float4 qv = *(const float4*)&qs[h][sub * 36 + (d4 << 2)];
        acc[h] = fmaf(qv.x, rvl[d4*4+0], acc[h]);
        acc[h] = fmaf(qv.y, rvl[d4*4+1], acc[h]);
        acc[h] = fmaf(qv.z, rvl[d4*4+2], acc[h]);
        acc[h] = fmaf(qv.w, rvl[d4*4+3], acc[h]);
      }
    }
#pragma unroll
    for (int h = 0; h < 8; ++h) {
      acc[h] += __shfl_xor(acc[h], 1);
      acc[h] += __shfl_xor(acc[h], 2);
    }
    const int h0 = sub << 1;
    scores[(((size_t)(b*8 + h0  ) * 512) + i) * 512 + j] = acc[h0];
    scores[(((size_t)(b*8 + h0+1) * 512) + i) * 512 + j] = acc[h0+1];
  }
}

// =====================================================================
// relation_v kernel: per (b,i) block, streams rv[b,i,:,:] and writes
// x[b,i,h*128+d] = sum_j p[b,h,i,j]*rv[b,i,j,d]  (p read as bf16)
// =====================================================================
__global__ __launch_bounds__(256)
void relv_kernel(const bf16* __restrict__ p16, const float* __restrict__ rvg,
                 float* __restrict__ x)
{
  const int bi = blockIdx.x, b = bi >> 9, i = bi & 511;
  __shared__ float ps[8][512];
  const int t = threadIdx.x;
  for (int u = t; u < 512; u += 256) {
    const int h = u >> 6, j0 = (u & 63) << 3;
    const bf16x8 v8 = *(const bf16x8*)&p16[(((size_t)(b*8 + h) * 512) + i) * 512 + j0];
    float4 lo, hi;
    lo.x = (float)v8[0]; lo.y = (float)v8[1]; lo.z = (float)v8[2]; lo.w = (float)v8[3];
    hi.x = (float)v8[4]; hi.y = (float)v8[5]; hi.z = (float)v8[6]; hi.w = (float)v8[7];
    *(float4*)&ps[h][j0]     = lo;
    *(float4*)&ps[h][j0 + 4] = hi;
  }
  __syncthreads();
  const int h = t >> 5, d0 = (t & 31) << 2;
  const float* rp = rvg + (size_t)bi * 512 * 128 + d0;
  float4 acc = make_float4(0.f, 0.f, 0.f, 0.f);
  for (int j = 0; j < 512; j += 8) {
    float4 rr[8];
#pragma unroll
    for (int u = 0; u < 8; ++u)
      rr[u] = *(const float4*)&rp[(size_t)(j + u) * 128];
#pragma unroll
    for (int u = 0; u < 8; ++u) {
      const float w = ps[h][j + u];
      acc.x = fmaf(w, rr[u].x, acc.x);
      acc.y = fmaf(w, rr[u].y, acc.y);
      acc.z = fmaf(w, rr[u].z, acc.z);
      acc.w = fmaf(w, rr[u].w, acc.w);
    }
  }
  *(float4*)&x[((size_t)(b * 512 + i)) * 1024 + h * 128 + d0] = acc;
}

// =====================================================================
// sep / gating / loss kernel (single block).
// =====================================================================
__global__ __launch_bounds__(256)
void sep_kernel(const float* __restrict__ qb, const float* __restrict__ hw,
                const int* __restrict__ sep_id, const float* __restrict__ hreg,
                float* __restrict__ g, float* __restrict__ loss_out)
{
  __shared__ float pool[16][4];
  __shared__ float spred[16][4];
  __shared__ float lbuf[16];
  __shared__ int sids[4];
  const int t = threadIdx.x;
  if (t < 4) sids[t] = sep_id[t];
  __syncthreads();
  {
    const int dot = t >> 2, sub = t & 3;
    const int bh = dot >> 2, n = dot & 3;
    const int b = bh >> 3, h = bh & 7;
    const int row = sids[n];
    const float* qp = qb + (((size_t)(b * 8 + h) * 512) + row) * 128 + sub * 32;
    const float* wp = hw + h * 128 + sub * 32;
    float s = 0.f;
#pragma unroll
    for (int dd = 0; dd < 32; ++dd) s = fmaf(qp[dd], wp[dd], s);
    s += __shfl_xor(s, 1);
    s += __shfl_xor(s, 2);
    if (sub == 0) { pool[bh][n] = s; }
  }
  __syncthreads();
  if (t < 16) {
    float pv[4];
#pragma unroll
    for (int n = 0; n < 4; ++n) pv[n] = pool[t][n];
    float mx = fmaxf(fmaxf(pv[0], pv[1]), fmaxf(pv[2], pv[3]));
    float sum = 0.f;
#pragma unroll
    for (int n = 0; n < 4; ++n) { pv[n] = expf(pv[n] - mx); sum += pv[n]; }
    const float inv = 1.f / sum;
    float maxp = 0.f, l2 = 0.f;
#pragma unroll
    for (int n = 0; n < 4; ++n) {
      const float pr = pv[n] * inv;
      spred[t][n] = pr;
      maxp = fmaxf(maxp, pr);
      const float tg = hreg[n];
      l2 += tg * (logf(tg) - logf(pr));
    }
    lbuf[t] = (1.f - maxp) / 16.f + l2 / 64.f;
  }
  __syncthreads();
  if (t == 0) {
    float L = 0.f;
#pragma unroll
    for (int r = 0; r < 16; ++r) L += lbuf[r];
    loss_out[0] = L;
  }
  for (int idx = t; idx < 16 * 512; idx += 256) {
    const int bh = idx >> 9, pp = idx & 511;
    float gg = 0.f;
#pragma unroll
    for (int n = 0; n < 4; ++n)
      gg += spred[bh][n] * (pp >= sids[n] ? 1.f : 0.f);
    g[idx] = gg;
  }
}

// =====================================================================
// softmax kernel: one wave per (b,h,i) row; writes bf16 p only.
// =====================================================================
__global__ __launch_bounds__(64)
void softmax_kernel(const float* __restrict__ scores, const int* __restrict__ mask,
                    const float* __restrict__ g, bf16* __restrict__ pb)
{
  const int bhi = blockIdx.x;
  const int i = bhi & 511;
  const int bh = bhi >> 9;
  const int b = bh >> 3;
  const float* row = scores + (size_t)bhi * 512;
  const int* mrow = mask + ((size_t)(b * 512 + i)) * 512;
  const float* grow = g + bh * 512;
  const float gi = grow[i];
  const int j0 = threadIdx.x << 3;
  float va[8];
  *(float4*)&va[0] = *(const float4*)&row[j0];
  *(float4*)&va[4] = *(const float4*)&row[j0 + 4];
  int ma[8];
  *(int4*)&ma[0] = *(const int4*)&mrow[j0];
  *(int4*)&ma[4] = *(const int4*)&mrow[j0 + 4];
  float ga[8];
  *(float4*)&ga[0] = *(const float4*)&grow[j0];
  *(float4*)&ga[4] = *(const float4*)&grow[j0 + 4];
  float mx = -3.402823466e+38f;
#pragma unroll
  for (int u = 0; u < 8; ++u) {
    const int j = j0 + u;
    float s = va[u] * SCALE;
    if (ma[u] == 0) s = -1.0e9f;
    const float fac = (j >= i) ? gi : ga[u];
    s *= fac;
    va[u] = s;
    mx = fmaxf(mx, s);
  }
#pragma unroll
  for (int off = 32; off > 0; off >>= 1) mx = fmaxf(mx, __shfl_xor(mx, off));
  float sum = 0.f;
#pragma unroll
  for (int u = 0; u < 8; ++u) { const float e = __expf(va[u] - mx); va[u] = e; sum += e; }
#pragma unroll
  for (int off = 32; off > 0; off >>= 1) sum += __shfl_xor(sum, off);
  const float inv = 1.f / sum;
  bf16 pb8[8];
#pragma unroll
  for (int u = 0; u < 8; ++u) { pb8[u] = (bf16)(va[u] * inv); }
  *(uint4*)&pb[(size_t)bhi * 512 + j0] = *(uint4*)&pb8[0];
}

// =====================================================================
extern "C" void kernel_launch(void* const* d_in, const int* in_sizes, int n_in,
                              void* d_out, int out_size, void* d_ws, size_t ws_size,
                              hipStream_t stream)
{
  const float* query = (const float*)d_in[0];
  const float* key   = (const float*)d_in[1];
  const float* value = (const float*)d_in[2];
  const float* rk    = (const float*)d_in[3];
  const float* rv    = (const float*)d_in[4];
  const int*   mask  = (const int*)d_in[5];
  const int*   sep   = (const int*)d_in[6];
  const float* hreg  = (const float*)d_in[7];
  const float* Wq    = (const float*)d_in[8];
  const float* bq    = (const float*)d_in[9];
  const float* Wk    = (const float*)d_in[10];
  const float* bk    = (const float*)d_in[11];
  const float* Wv    = (const float*)d_in[12];
  const float* bv    = (const float*)d_in[13];
  const float* Wo    = (const float*)d_in[14];
  const float* bo    = (const float*)d_in[15];
  const float* hw    = (const float*)d_in[16];
  float* out = (float*)d_out;

  float* ws = (float*)d_ws;
  float* qb  = ws;                 // 1,048,576 f32
  float* sc  = qb  + 1048576;      // 4,194,304 f32
  float* xb  = sc  + 4194304;      // 1,048,576 f32
  float* gb  = xb  + 1048576;      //     8,192 f32
  bf16* qb16 = (bf16*)(gb + 8192);           // 1,048,576 bf16
  bf16* kb16 = qb16 + 1048576;               // 1,048,576 bf16
  bf16* vb16 = kb16 + 1048576;               // 1,048,576 bf16
  bf16* vt16 = vb16 + 1048576;               // 1,048,576 bf16
  bf16* pb16 = vt16 + 1048576;               // 4,194,304 bf16

  proj3_mfma<<<dim3(256, 3), 256, 0, stream>>>(query, key, value,
                                               Wq, Wk, Wv, bq, bk, bv,
                                               qb, qb16, kb16, vb16);
  vtrans<<<dim3(16, 16), 256, 0, stream>>>(vb16, vt16);
  sep_kernel<<<dim3(1), 256, 0, stream>>>(qb, hw, sep, hreg, gb, out + 1048576);
  relk_kernel<<<dim3(1024), 256, 0, stream>>>(qb, rk, sc);
  qk_mfma<<<dim3(64, 16), 256, 0, stream>>>(qb16, kb16, sc);
  softmax_kernel<<<dim3(8192), 64, 0, stream>>>(sc, mask, gb, pb16);
  relv_kernel<<<dim3(1024), 256, 0, stream>>>(pb16, rv, xb);
  pv_mfma<<<dim3(16, 16), 256, 0, stream>>>(pb16, vt16, xb);
  proj_out<<<dim3(256), 256, 0, stream>>>(xb, Wo, bo, out);
}

// Round 4
// 233.218 us; speedup vs baseline: 2.1419x; 1.1711x over previous
//
#include <hip/hip_runtime.h>

static constexpr float SCALE = 0.08838834764831845f; // 1/sqrt(128)

typedef __bf16 bf16;
typedef __bf16 bf16x8 __attribute__((ext_vector_type(8)));
typedef float  f32x4  __attribute__((ext_vector_type(4)));

#define MFMA16(a, b, c) __builtin_amdgcn_mfma_f32_16x16x32_bf16((a), (b), (c), 0, 0, 0)

__device__ inline bf16x8 cvt8(const float4& x, const float4& y) {
  bf16x8 r;
  r[0] = (bf16)x.x; r[1] = (bf16)x.y; r[2] = (bf16)x.z; r[3] = (bf16)x.w;
  r[4] = (bf16)y.x; r[5] = (bf16)y.y; r[6] = (bf16)y.z; r[7] = (bf16)y.w;
  return r;
}

// =====================================================================
// Batched projection GEMM (q,k,v in one launch; blockIdx.y selects).
// sel==0 (q): fp32 qf + bf16 q16 in [b,h,i,dk]
// sel==1 (k): bf16 k16 in [b,h,i,dk]
// sel==2 (v): bf16 vt16 TRANSPOSED [b,h,dk,i]  (direct, no vtrans pass)
// =====================================================================
__global__ __launch_bounds__(256)
void proj3_mfma(const float* __restrict__ Aq, const float* __restrict__ Ak,
                const float* __restrict__ Av,
                const float* __restrict__ Wq, const float* __restrict__ Wk,
                const float* __restrict__ Wv,
                const float* __restrict__ bq, const float* __restrict__ bk,
                const float* __restrict__ bv,
                float* __restrict__ qf,
                bf16* __restrict__ q16, bf16* __restrict__ k16,
                bf16* __restrict__ vt16)
{
  const int sel = blockIdx.y;
  const float* A    = sel == 0 ? Aq : (sel == 1 ? Ak : Av);
  const float* W    = sel == 0 ? Wq : (sel == 1 ? Wk : Wv);
  const float* bias = sel == 0 ? bq : (sel == 1 ? bk : bv);

  __shared__ bf16 As[64][72];
  __shared__ bf16 Bs[64][72];
  const int t = threadIdx.x;
  const int m0 = (blockIdx.x >> 4) << 6;
  const int n0 = (blockIdx.x & 15) << 6;
  const int wave = t >> 6, lane = t & 63;
  const int wr = wave >> 1, wc = wave & 1;
  const int srow = t >> 2, skc = (t & 3) << 4;
  const float* Ap = A + (size_t)(m0 + srow) * 1024 + skc;
  const float* Wp = W + (size_t)(n0 + srow) * 1024 + skc;
  const int fr = lane & 15, kb = (lane >> 4) << 3;
  f32x4 acc[2][2];
#pragma unroll
  for (int i = 0; i < 2; ++i)
#pragma unroll
    for (int j = 0; j < 2; ++j) acc[i][j] = (f32x4){0.f, 0.f, 0.f, 0.f};

  float4 a4[4], w4[4], a4n[4], w4n[4];
#pragma unroll
  for (int u = 0; u < 4; ++u) {
    a4[u] = *(const float4*)(Ap + u * 4);
    w4[u] = *(const float4*)(Wp + u * 4);
  }
  for (int k0 = 0; k0 < 1024; k0 += 64) {
    __syncthreads();
    *(bf16x8*)&As[srow][skc]     = cvt8(a4[0], a4[1]);
    *(bf16x8*)&As[srow][skc + 8] = cvt8(a4[2], a4[3]);
    *(bf16x8*)&Bs[srow][skc]     = cvt8(w4[0], w4[1]);
    *(bf16x8*)&Bs[srow][skc + 8] = cvt8(w4[2], w4[3]);
    __syncthreads();
    if (k0 + 64 < 1024) {
#pragma unroll
      for (int u = 0; u < 4; ++u) {
        a4n[u] = *(const float4*)(Ap + k0 + 64 + u * 4);
        w4n[u] = *(const float4*)(Wp + k0 + 64 + u * 4);
      }
    }
#pragma unroll
    for (int ks = 0; ks < 2; ++ks) {
      bf16x8 af[2], bff[2];
#pragma unroll
      for (int f = 0; f < 2; ++f) {
        af[f]  = *(const bf16x8*)&As[wr * 32 + f * 16 + fr][ks * 32 + kb];
        bff[f] = *(const bf16x8*)&Bs[wc * 32 + f * 16 + fr][ks * 32 + kb];
      }
#pragma unroll
      for (int i = 0; i < 2; ++i)
#pragma unroll
        for (int j = 0; j < 2; ++j)
          acc[i][j] = MFMA16(af[i], bff[j], acc[i][j]);
    }
#pragma unroll
    for (int u = 0; u < 4; ++u) { a4[u] = a4n[u]; w4[u] = w4n[u]; }
  }
  const int lrow = (lane >> 4) << 2, lcol = lane & 15;
#pragma unroll
  for (int i = 0; i < 2; ++i) {
#pragma unroll
    for (int j = 0; j < 2; ++j) {
      const int n = n0 + wc * 32 + j * 16 + lcol;
      const float bvl = bias[n];
#pragma unroll
      for (int r = 0; r < 4; ++r) {
        const int m = m0 + wr * 32 + i * 16 + lrow + r;
        const float val = acc[i][j][r] + bvl;
        const int b = m >> 9, ii = m & 511, h = n >> 7, dk = n & 127;
        if (sel == 2) {
          vt16[(((size_t)(b * 8 + h) * 128) + dk) * 512 + ii] = (bf16)val;
        } else {
          const size_t idx = (((size_t)(b * 8 + h) * 512) + ii) * 128 + dk;
          if (sel == 0) { qf[idx] = val; q16[idx] = (bf16)val; }
          else          { k16[idx] = (bf16)val; }
        }
      }
    }
  }
}

// =====================================================================
// Output projection: Cf[m*1024+n] = A @ W^T + bias (A = xb fp32)
// =====================================================================
__global__ __launch_bounds__(256)
void proj_out(const float* __restrict__ A, const float* __restrict__ W,
              const float* __restrict__ bias, float* __restrict__ Cf)
{
  __shared__ bf16 As[64][72];
  __shared__ bf16 Bs[64][72];
  const int t = threadIdx.x;
  const int m0 = (blockIdx.x >> 4) << 6;
  const int n0 = (blockIdx.x & 15) << 6;
  const int wave = t >> 6, lane = t & 63;
  const int wr = wave >> 1, wc = wave & 1;
  const int srow = t >> 2, skc = (t & 3) << 4;
  const float* Ap = A + (size_t)(m0 + srow) * 1024 + skc;
  const float* Wp = W + (size_t)(n0 + srow) * 1024 + skc;
  const int fr = lane & 15, kb = (lane >> 4) << 3;
  f32x4 acc[2][2];
#pragma unroll
  for (int i = 0; i < 2; ++i)
#pragma unroll
    for (int j = 0; j < 2; ++j) acc[i][j] = (f32x4){0.f, 0.f, 0.f, 0.f};

  float4 a4[4], w4[4], a4n[4], w4n[4];
#pragma unroll
  for (int u = 0; u < 4; ++u) {
    a4[u] = *(const float4*)(Ap + u * 4);
    w4[u] = *(const float4*)(Wp + u * 4);
  }
  for (int k0 = 0; k0 < 1024; k0 += 64) {
    __syncthreads();
    *(bf16x8*)&As[srow][skc]     = cvt8(a4[0], a4[1]);
    *(bf16x8*)&As[srow][skc + 8] = cvt8(a4[2], a4[3]);
    *(bf16x8*)&Bs[srow][skc]     = cvt8(w4[0], w4[1]);
    *(bf16x8*)&Bs[srow][skc + 8] = cvt8(w4[2], w4[3]);
    __syncthreads();
    if (k0 + 64 < 1024) {
#pragma unroll
      for (int u = 0; u < 4; ++u) {
        a4n[u] = *(const float4*)(Ap + k0 + 64 + u * 4);
        w4n[u] = *(const float4*)(Wp + k0 + 64 + u * 4);
      }
    }
#pragma unroll
    for (int ks = 0; ks < 2; ++ks) {
      bf16x8 af[2], bff[2];
#pragma unroll
      for (int f = 0; f < 2; ++f) {
        af[f]  = *(const bf16x8*)&As[wr * 32 + f * 16 + fr][ks * 32 + kb];
        bff[f] = *(const bf16x8*)&Bs[wc * 32 + f * 16 + fr][ks * 32 + kb];
      }
#pragma unroll
      for (int i = 0; i < 2; ++i)
#pragma unroll
        for (int j = 0; j < 2; ++j)
          acc[i][j] = MFMA16(af[i], bff[j], acc[i][j]);
    }
#pragma unroll
    for (int u = 0; u < 4; ++u) { a4[u] = a4n[u]; w4[u] = w4n[u]; }
  }
  const int lrow = (lane >> 4) << 2, lcol = lane & 15;
#pragma unroll
  for (int i = 0; i < 2; ++i) {
#pragma unroll
    for (int j = 0; j < 2; ++j) {
      const int n = n0 + wc * 32 + j * 16 + lcol;
      const float bvl = bias[n];
#pragma unroll
      for (int r = 0; r < 4; ++r) {
        const int m = m0 + wr * 32 + i * 16 + lrow + r;
        Cf[(size_t)m * 1024 + n] = acc[i][j][r] + bvl;
      }
    }
  }
}

// =====================================================================
// QK^T MFMA: scores[bh] = q16[bh] @ k16[bh]^T  (overwrite, no RMW)
// =====================================================================
__global__ __launch_bounds__(256)
void qk_mfma(const bf16* __restrict__ Q, const bf16* __restrict__ Kb,
             float* __restrict__ scores)
{
  const int bh = blockIdx.y;
  const bf16* A = Q  + (size_t)bh * (512 * 128);
  const bf16* B = Kb + (size_t)bh * (512 * 128);
  float* C = scores + (size_t)bh * (512 * 512);
  const int m0 = (blockIdx.x >> 3) << 6, n0 = (blockIdx.x & 7) << 6;
  __shared__ bf16 As[64][72];
  __shared__ bf16 Bs[64][72];
  const int t = threadIdx.x, wave = t >> 6, lane = t & 63;
  const int wr = wave >> 1, wc = wave & 1;
  const int srow = t >> 2, skc = (t & 3) << 4;
  const int fr = lane & 15, kb = (lane >> 4) << 3;
  f32x4 acc[2][2];
#pragma unroll
  for (int i = 0; i < 2; ++i)
#pragma unroll
    for (int j = 0; j < 2; ++j) acc[i][j] = (f32x4){0.f, 0.f, 0.f, 0.f};

  const bf16* ap = A + (size_t)(m0 + srow) * 128 + skc;
  const bf16* bp = B + (size_t)(n0 + srow) * 128 + skc;
  uint4 a0 = *(const uint4*)ap, a1 = *(const uint4*)(ap + 8);
  uint4 b0 = *(const uint4*)bp, b1 = *(const uint4*)(bp + 8);
  for (int k0 = 0; k0 < 128; k0 += 64) {
    __syncthreads();
    *(uint4*)&As[srow][skc]     = a0; *(uint4*)&As[srow][skc + 8] = a1;
    *(uint4*)&Bs[srow][skc]     = b0; *(uint4*)&Bs[srow][skc + 8] = b1;
    __syncthreads();
    if (k0 == 0) {
      a0 = *(const uint4*)(ap + 64); a1 = *(const uint4*)(ap + 72);
      b0 = *(const uint4*)(bp + 64); b1 = *(const uint4*)(bp + 72);
    }
#pragma unroll
    for (int ks = 0; ks < 2; ++ks) {
      bf16x8 af[2], bff[2];
#pragma unroll
      for (int f = 0; f < 2; ++f) {
        af[f]  = *(const bf16x8*)&As[wr * 32 + f * 16 + fr][ks * 32 + kb];
        bff[f] = *(const bf16x8*)&Bs[wc * 32 + f * 16 + fr][ks * 32 + kb];
      }
#pragma unroll
      for (int i = 0; i < 2; ++i)
#pragma unroll
        for (int j = 0; j < 2; ++j)
          acc[i][j] = MFMA16(af[i], bff[j], acc[i][j]);
    }
  }
  const int lrow = (lane >> 4) << 2, lcol = lane & 15;
#pragma unroll
  for (int i = 0; i < 2; ++i)
#pragma unroll
    for (int j = 0; j < 2; ++j)
#pragma unroll
      for (int r = 0; r < 4; ++r) {
        const int m = m0 + wr * 32 + i * 16 + lrow + r;
        const int n = n0 + wc * 32 + j * 16 + lcol;
        C[(size_t)m * 512 + n] = acc[i][j][r];
      }
}

// =====================================================================
// PV MFMA: x[b,i,h*128+n] += p16[bh] @ vt16[bh] (W-form, K=512)
// =====================================================================
__global__ __launch_bounds__(256)
void pv_mfma(const bf16* __restrict__ P, const bf16* __restrict__ VT,
             float* __restrict__ x)
{
  const int bh = blockIdx.y, b = bh >> 3, h = bh & 7;
  const bf16* A = P  + (size_t)bh * (512 * 512);
  const bf16* B = VT + (size_t)bh * (128 * 512);
  float* C = x + (size_t)b * (512 * 1024) + h * 128;
  const int m0 = (blockIdx.x >> 1) << 6, n0 = (blockIdx.x & 1) << 6;
  __shared__ bf16 As[64][72];
  __shared__ bf16 Bs[64][72];
  const int t = threadIdx.x, wave = t >> 6, lane = t & 63;
  const int wr = wave >> 1, wc = wave & 1;
  const int srow = t >> 2, skc = (t & 3) << 4;
  const int fr = lane & 15, kb = (lane >> 4) << 3;
  f32x4 acc[2][2];
#pragma unroll
  for (int i = 0; i < 2; ++i)
#pragma unroll
    for (int j = 0; j < 2; ++j) acc[i][j] = (f32x4){0.f, 0.f, 0.f, 0.f};

  const bf16* ap = A + (size_t)(m0 + srow) * 512 + skc;
  const bf16* bp = B + (size_t)(n0 + srow) * 512 + skc;
  uint4 a0 = *(const uint4*)ap, a1 = *(const uint4*)(ap + 8);
  uint4 b0 = *(const uint4*)bp, b1 = *(const uint4*)(bp + 8);
  for (int k0 = 0; k0 < 512; k0 += 64) {
    __syncthreads();
    *(uint4*)&As[srow][skc]     = a0; *(uint4*)&As[srow][skc + 8] = a1;
    *(uint4*)&Bs[srow][skc]     = b0; *(uint4*)&Bs[srow][skc + 8] = b1;
    __syncthreads();
    if (k0 + 64 < 512) {
      a0 = *(const uint4*)(ap + k0 + 64); a1 = *(const uint4*)(ap + k0 + 72);
      b0 = *(const uint4*)(bp + k0 + 64); b1 = *(const uint4*)(bp + k0 + 72);
    }
#pragma unroll
    for (int ks = 0; ks < 2; ++ks) {
      bf16x8 af[2], bff[2];
#pragma unroll
      for (int f = 0; f < 2; ++f) {
        af[f]  = *(const bf16x8*)&As[wr * 32 + f * 16 + fr][ks * 32 + kb];
        bff[f] = *(const bf16x8*)&Bs[wc * 32 + f * 16 + fr][ks * 32 + kb];
      }
#pragma unroll
      for (int i = 0; i < 2; ++i)
#pragma unroll
        for (int j = 0; j < 2; ++j)
          acc[i][j] = MFMA16(af[i], bff[j], acc[i][j]);
    }
  }
  const int lrow = (lane >> 4) << 2, lcol = lane & 15;
#pragma unroll
  for (int i = 0; i < 2; ++i)
#pragma unroll
    for (int j = 0; j < 2; ++j)
#pragma unroll
      for (int r = 0; r < 4; ++r) {
        const int m = m0 + wr * 32 + i * 16 + lrow + r;
        const int n = n0 + wc * 32 + j * 16 + lcol;
        C[(size_t)m * 1024 + n] += acc[i][j][r];
      }
}

// =====================================================================
// fused_sm: per (b,i) block.
// Phase 1: stream rk[b,i,:,:], rel[h][j] = q[b,h,i,:].rk[b,i,j,:] -> LDS
// Phase 2: s = (sc + rel)*SCALE, mask, *factor, softmax -> pb16
// =====================================================================
__global__ __launch_bounds__(256)
void fused_sm(const float* __restrict__ qf, const float* __restrict__ rk,
              const float* __restrict__ sc, const int* __restrict__ mask,
              const float* __restrict__ g, bf16* __restrict__ pb)
{
  const int bi = blockIdx.x;
  const int b = bi >> 9, i = bi & 511;
  __shared__ float qs[8][144];
  __shared__ float rel[8][516];
  const int t = threadIdx.x;
  {
    const int h = t >> 5, d0 = (t & 31) << 2;
    const int sub2 = d0 >> 5, dd = d0 & 31;
    const float4 qv = *(const float4*)&qf[(((size_t)(b * 8 + h) * 512) + i) * 128 + d0];
    *(float4*)&qs[h][sub2 * 36 + dd] = qv;
  }
  __syncthreads();
  const int jj = t >> 2, sub = t & 3;
  for (int jp = 0; jp < 512; jp += 64) {
    const int j = jp + jj;
    const float* rkp = rk + ((size_t)bi * 512 + j) * 128 + sub * 32;
    float rvl[32];
#pragma unroll
    for (int u = 0; u < 8; ++u)
      *(float4*)&rvl[u * 4] = *(const float4*)&rkp[u * 4];
    float acc[8];
#pragma unroll
    for (int h = 0; h < 8; ++h) acc[h] = 0.f;
#pragma unroll
    for (int d4 = 0; d4 < 8; ++d4) {
#pragma unroll
      for (int h = 0; h < 8; ++h) {
        const float4 qv = *(const float4*)&qs[h][sub * 36 + (d4 << 2)];
        acc[h] = fmaf(qv.x, rvl[d4*4+0], acc[h]);
        acc[h] = fmaf(qv.y, rvl[d4*4+1], acc[h]);
        acc[h] = fmaf(qv.z, rvl[d4*4+2], acc[h]);
        acc[h] = fmaf(qv.w, rvl[d4*4+3], acc[h]);
      }
    }
#pragma unroll
    for (int h = 0; h < 8; ++h) {
      acc[h] += __shfl_xor(acc[h], 1);
      acc[h] += __shfl_xor(acc[h], 2);
    }
    const int h0 = sub << 1;
    rel[h0][j]     = acc[h0];
    rel[h0 + 1][j] = acc[h0 + 1];
  }
  __syncthreads();
  // phase 2: softmax per head row
  const int h = t >> 5, ln = t & 31;
  const float* scrow = sc + (((size_t)(b * 8 + h) * 512) + i) * 512;
  const int* mrow = mask + ((size_t)(b * 512 + i)) * 512;
  const float* grow = g + (b * 8 + h) * 512;
  const float gi = grow[i];
  float s[16];
  float mx = -3.402823466e+38f;
#pragma unroll
  for (int k = 0; k < 16; ++k) {
    const int j = ln + (k << 5);
    float sv = (scrow[j] + rel[h][j]) * SCALE;
    if (mrow[j] == 0) sv = -1.0e9f;
    const float fac = (j >= i) ? gi : grow[j];
    sv *= fac;
    s[k] = sv;
    mx = fmaxf(mx, sv);
  }
#pragma unroll
  for (int off = 16; off > 0; off >>= 1) mx = fmaxf(mx, __shfl_xor(mx, off));
  float sum = 0.f;
#pragma unroll
  for (int k = 0; k < 16; ++k) { const float e = __expf(s[k] - mx); s[k] = e; sum += e; }
#pragma unroll
  for (int off = 16; off > 0; off >>= 1) sum += __shfl_xor(sum, off);
  const float inv = 1.f / sum;
  bf16* prow = pb + (((size_t)(b * 8 + h) * 512) + i) * 512;
#pragma unroll
  for (int k = 0; k < 16; ++k) {
    const int j = ln + (k << 5);
    prow[j] = (bf16)(s[k] * inv);
  }
}

// =====================================================================
// fused_out (relation_v): per (b,i) block, j-group decomposition.
// 8 groups x 32 lanes; group g handles j = g, g+8, ...; each rv element
// loaded exactly once.  x[b,i,h*128+d] = sum_j p[h,j]*rv[j,d]
// =====================================================================
__global__ __launch_bounds__(256)
void fused_out(const bf16* __restrict__ pb, const float* __restrict__ rvg,
               float* __restrict__ x)
{
  const int bi = blockIdx.x, b = bi >> 9, i = bi & 511;
  __shared__ float smem[8192];           // red: [8g][8h][128d]; ps aliases
  float* ps = smem;                      // ps[h][j] stride 520 (first 4160)
  const int t = threadIdx.x;
  {
    const int h = t >> 5, seg = t & 31;  // 16 j per thread
    const int j0 = seg << 4;
    const bf16x8 v0 = *(const bf16x8*)&pb[(((size_t)(b*8 + h) * 512) + i) * 512 + j0];
    const bf16x8 v1 = *(const bf16x8*)&pb[(((size_t)(b*8 + h) * 512) + i) * 512 + j0 + 8];
#pragma unroll
    for (int u = 0; u < 8; ++u) ps[h * 520 + j0 + u]     = (float)v0[u];
#pragma unroll
    for (int u = 0; u < 8; ++u) ps[h * 520 + j0 + 8 + u] = (float)v1[u];
  }
  __syncthreads();
  const int gq = t >> 5, ln = t & 31, d0 = ln << 2;
  f32x4 acc[8];
#pragma unroll
  for (int h = 0; h < 8; ++h) acc[h] = (f32x4){0.f, 0.f, 0.f, 0.f};
  const float* rp = rvg + (size_t)bi * 512 * 128 + d0;
  for (int j = gq; j < 512; j += 8) {
    const float4 rr = *(const float4*)&rp[(size_t)j * 128];
#pragma unroll
    for (int h = 0; h < 8; ++h) {
      const float w = ps[h * 520 + j];
      acc[h][0] = fmaf(w, rr.x, acc[h][0]);
      acc[h][1] = fmaf(w, rr.y, acc[h][1]);
      acc[h][2] = fmaf(w, rr.z, acc[h][2]);
      acc[h][3] = fmaf(w, rr.w, acc[h][3]);
    }
  }
  __syncthreads();           // done reading ps; smem becomes red
#pragma unroll
  for (int h = 0; h < 8; ++h)
    *(f32x4*)&smem[((gq << 3) + h) * 128 + d0] = acc[h];
  __syncthreads();
  {
    const int h = t >> 5;    // reuse (h, d0) mapping for final sum
    float4 r = make_float4(0.f, 0.f, 0.f, 0.f);
#pragma unroll
    for (int gg = 0; gg < 8; ++gg) {
      const float4 v = *(const float4*)&smem[((gg << 3) + h) * 128 + d0];
      r.x += v.x; r.y += v.y; r.z += v.z; r.w += v.w;
    }
    *(float4*)&x[((size_t)(b * 512 + i)) * 1024 + h * 128 + d0] = r;
  }
}

// =====================================================================
// sep / gating / loss kernel (single block).
// =====================================================================
__global__ __launch_bounds__(256)
void sep_kernel(const float* __restrict__ qb, const float* __restrict__ hw,
                const int* __restrict__ sep_id, const float* __restrict__ hreg,
                float* __restrict__ g, float* __restrict__ loss_out)
{
  __shared__ float pool[16][4];
  __shared__ float spred[16][4];
  __shared__ float lbuf[16];
  __shared__ int sids[4];
  const int t = threadIdx.x;
  if (t < 4) sids[t] = sep_id[t];
  __syncthreads();
  {
    const int dot = t >> 2, sub = t & 3;
    const int bh = dot >> 2, n = dot & 3;
    const int b = bh >> 3, h = bh & 7;
    const int row = sids[n];
    const float* qp = qb + (((size_t)(b * 8 + h) * 512) + row) * 128 + sub * 32;
    const float* wp = hw + h * 128 + sub * 32;
    float s = 0.f;
#pragma unroll
    for (int dd = 0; dd < 32; ++dd) s = fmaf(qp[dd], wp[dd], s);
    s += __shfl_xor(s, 1);
    s += __shfl_xor(s, 2);
    if (sub == 0) { pool[bh][n] = s; }
  }
  __syncthreads();
  if (t < 16) {
    float pv[4];
#pragma unroll
    for (int n = 0; n < 4; ++n) pv[n] = pool[t][n];
    float mx = fmaxf(fmaxf(pv[0], pv[1]), fmaxf(pv[2], pv[3]));
    float sum = 0.f;
#pragma unroll
    for (int n = 0; n < 4; ++n) { pv[n] = expf(pv[n] - mx); sum += pv[n]; }
    const float inv = 1.f / sum;
    float maxp = 0.f, l2 = 0.f;
#pragma unroll
    for (int n = 0; n < 4; ++n) {
      const float pr = pv[n] * inv;
      spred[t][n] = pr;
      maxp = fmaxf(maxp, pr);
      const float tg = hreg[n];
      l2 += tg * (logf(tg) - logf(pr));
    }
    lbuf[t] = (1.f - maxp) / 16.f + l2 / 64.f;
  }
  __syncthreads();
  if (t == 0) {
    float L = 0.f;
#pragma unroll
    for (int r = 0; r < 16; ++r) L += lbuf[r];
    loss_out[0] = L;
  }
  for (int idx = t; idx < 16 * 512; idx += 256) {
    const int bh = idx >> 9, pp = idx & 511;
    float gg = 0.f;
#pragma unroll
    for (int n = 0; n < 4; ++n)
      gg += spred[bh][n] * (pp >= sids[n] ? 1.f : 0.f);
    g[idx] = gg;
  }
}

// =====================================================================
extern "C" void kernel_launch(void* const* d_in, const int* in_sizes, int n_in,
                              void* d_out, int out_size, void* d_ws, size_t ws_size,
                              hipStream_t stream)
{
  const float* query = (const float*)d_in[0];
  const float* key   = (const float*)d_in[1];
  const float* value = (const float*)d_in[2];
  const float* rk    = (const float*)d_in[3];
  const float* rv    = (const float*)d_in[4];
  const int*   mask  = (const int*)d_in[5];
  const int*   sep   = (const int*)d_in[6];
  const float* hreg  = (const float*)d_in[7];
  const float* Wq    = (const float*)d_in[8];
  const float* bq    = (const float*)d_in[9];
  const float* Wk    = (const float*)d_in[10];
  const float* bk    = (const float*)d_in[11];
  const float* Wv    = (const float*)d_in[12];
  const float* bv    = (const float*)d_in[13];
  const float* Wo    = (const float*)d_in[14];
  const float* bo    = (const float*)d_in[15];
  const float* hw    = (const float*)d_in[16];
  float* out = (float*)d_out;

  float* ws = (float*)d_ws;
  float* qb  = ws;                 // 1,048,576 f32
  float* sc  = qb  + 1048576;      // 4,194,304 f32
  float* xb  = sc  + 4194304;      // 1,048,576 f32
  float* gb  = xb  + 1048576;      //     8,192 f32
  bf16* qb16 = (bf16*)(gb + 8192);           // 1,048,576 bf16
  bf16* kb16 = qb16 + 1048576;               // 1,048,576 bf16
  bf16* vt16 = kb16 + 1048576;               // 1,048,576 bf16
  bf16* pb16 = vt16 + 1048576;               // 4,194,304 bf16

  proj3_mfma<<<dim3(256, 3), 256, 0, stream>>>(query, key, value,
                                               Wq, Wk, Wv, bq, bk, bv,
                                               qb, qb16, kb16, vt16);
  qk_mfma<<<dim3(64, 16), 256, 0, stream>>>(qb16, kb16, sc);
  sep_kernel<<<dim3(1), 256, 0, stream>>>(qb, hw, sep, hreg, gb, out + 1048576);
  fused_sm<<<dim3(1024), 256, 0, stream>>>(qb, rk, sc, mask, gb, pb16);
  fused_out<<<dim3(1024), 256, 0, stream>>>(pb16, rv, xb);
  pv_mfma<<<dim3(16, 16), 256, 0, stream>>>(pb16, vt16, xb);
  proj_out<<<dim3(256), 256, 0, stream>>>(xb, Wo, bo, out);
}